// Round 11
// baseline (150.393 us; speedup 1.0000x reference)
//
#include <hip/hip_runtime.h>

// InfiniAttn forward on gfx950.
// cvt h->bf16 | transpose W->bf16 (merged) | GEMM qkv | V-transpose | flash attn
// SPLIT-KV ACROSS BLOCKS (z=2, 256-thr, fixed-max softmax => partials sum) with
// REDUCED REGISTER LIVENESS (jb-split QK/PV, VALU l-tree) at 4 waves/SIMD |
// combine+mem-gate | GEMM out 64x128 | +h,LN.

typedef unsigned short ushort_t;
typedef unsigned int uint32;

typedef __bf16 bf16x8 __attribute__((ext_vector_type(8)));
typedef float f32x4 __attribute__((ext_vector_type(4)));
typedef float f32x16 __attribute__((ext_vector_type(16)));
typedef unsigned short u16x8 __attribute__((ext_vector_type(8)));
typedef unsigned short u16x4 __attribute__((ext_vector_type(4)));
typedef unsigned int u32x4 __attribute__((ext_vector_type(4)));

typedef const __attribute__((address_space(1))) void gvoid_t;
typedef __attribute__((address_space(3))) void lvoid_t;

#define S_LEN 2048
#define BATCH 2
#define NHEAD 16

__device__ __forceinline__ ushort_t f2bf(float x) {
  union { float f; unsigned u; } c; c.f = x;
  unsigned r = (c.u + 0x7FFFu + ((c.u >> 16) & 1u)) >> 16;
  return (ushort_t)r;
}
__device__ __forceinline__ float bf2f(ushort_t v) {
  union { unsigned u; float f; } c; c.u = ((unsigned)v) << 16;
  return c.f;
}

// ---------------- dtype convert: h (fp32) -> bf16 ----------------
__global__ __launch_bounds__(256) void k_cvt_h(const float* __restrict__ src,
                                               ushort_t* __restrict__ dst, int n4) {
  int idx = blockIdx.x * 256 + threadIdx.x;
  if (idx >= n4) return;
  float4 v = ((const float4*)src)[idx];
  u16x4 o; o[0] = f2bf(v.x); o[1] = f2bf(v.y); o[2] = f2bf(v.z); o[3] = f2bf(v.w);
  ((u16x4*)dst)[idx] = o;
}

// ------------- transpose-convert (merged): W[K][N] fp32 -> WT[N][K] bf16 -------------
__global__ __launch_bounds__(256) void k_cvt_wT3(const float* __restrict__ Wq,
                                                 const float* __restrict__ Wkv,
                                                 const float* __restrict__ Wo,
                                                 ushort_t* __restrict__ wT,
                                                 ushort_t* __restrict__ woT) {
  const int z = blockIdx.z;
  const float* W;
  ushort_t* WT;
  int N;
  if (z == 0)      { W = Wq;  WT = wT;                          N = 1024; }
  else if (z == 1) { W = Wkv; WT = wT + (size_t)1024 * 1024;    N = 2048; }
  else             { W = Wo;  WT = woT;                         N = 1024; }
  const int K = 1024;
  if (blockIdx.x * 32 >= N) return;
  __shared__ float tile[32][33];
  const int n0 = blockIdx.x * 32, k0 = blockIdx.y * 32;
  const int tx = threadIdx.x & 31, ty = threadIdx.x >> 5;
#pragma unroll
  for (int r = 0; r < 32; r += 8)
    tile[ty + r][tx] = W[(size_t)(k0 + ty + r) * N + n0 + tx];
  __syncthreads();
#pragma unroll
  for (int r = 0; r < 32; r += 8)
    WT[(size_t)(n0 + ty + r) * K + k0 + tx] = f2bf(tile[tx][ty + r]);
}

// ------------- GEMM 128x128: C = A[M][K](bf16) * B[N][K]^T(bf16) -------------
template <int OUT_BF16>
__global__ __launch_bounds__(256) void k_gemm_bt(const ushort_t* __restrict__ A,
                                                 const ushort_t* __restrict__ B,
                                                 void* __restrict__ Cv, int M, int N, int K,
                                                 int nbx) {
  __shared__ __attribute__((aligned(16))) ushort_t As[128 * 32];
  __shared__ __attribute__((aligned(16))) ushort_t Bs[128 * 32];
  const int per = gridDim.x >> 3;  // grid % 8 == 0
  const int fl = (blockIdx.x & 7) * per + (blockIdx.x >> 3);
  const int m0 = (fl / nbx) * 128, n0 = (fl % nbx) * 128;
  const int tid = threadIdx.x, w = tid >> 6, lane = tid & 63;
  const int wm = (w >> 1) * 64, wn = (w & 1) * 64;
  const int l15 = lane & 15, l4 = lane >> 4;
  f32x4 acc[4][4];
#pragma unroll
  for (int i = 0; i < 4; ++i)
#pragma unroll
    for (int j = 0; j < 4; ++j)
#pragma unroll
      for (int r = 0; r < 4; ++r) acc[i][j][r] = 0.f;

  for (int k0 = 0; k0 < K; k0 += 32) {
    __syncthreads();
#pragma unroll
    for (int r = 0; r < 2; ++r) {
      int c = r * 256 + w * 64 + lane;
      const ushort_t* ga = A + (size_t)(m0 + (c >> 2)) * K + k0 + (c & 3) * 8;
      const ushort_t* gb = B + (size_t)(n0 + (c >> 2)) * K + k0 + (c & 3) * 8;
      __builtin_amdgcn_global_load_lds((gvoid_t*)ga, (lvoid_t*)(As + (r * 256 + w * 64) * 8), 16, 0, 0);
      __builtin_amdgcn_global_load_lds((gvoid_t*)gb, (lvoid_t*)(Bs + (r * 256 + w * 64) * 8), 16, 0, 0);
    }
    __syncthreads();
    bf16x8 af[4], bfr[4];
#pragma unroll
    for (int i = 0; i < 4; ++i) af[i] = *(const bf16x8*)&As[(wm + i * 16 + l15) * 32 + l4 * 8];
#pragma unroll
    for (int j = 0; j < 4; ++j) bfr[j] = *(const bf16x8*)&Bs[(wn + j * 16 + l15) * 32 + l4 * 8];
#pragma unroll
    for (int i = 0; i < 4; ++i)
#pragma unroll
      for (int j = 0; j < 4; ++j)
        acc[i][j] = __builtin_amdgcn_mfma_f32_16x16x32_bf16(af[i], bfr[j], acc[i][j], 0, 0, 0);
  }
#pragma unroll
  for (int i = 0; i < 4; ++i)
#pragma unroll
    for (int j = 0; j < 4; ++j)
#pragma unroll
      for (int r = 0; r < 4; ++r) {
        int row = m0 + wm + i * 16 + l4 * 4 + r;
        int col = n0 + wn + j * 16 + l15;
        if (OUT_BF16)
          ((ushort_t*)Cv)[(size_t)row * N + col] = f2bf(acc[i][j][r]);
        else
          ((float*)Cv)[(size_t)row * N + col] = acc[i][j][r];
      }
}

// ------------- GEMM 64x128 tiles (M=4096,N=1024: 512 blocks = 2/CU) -------------
__global__ __launch_bounds__(256) void k_gemm64(const ushort_t* __restrict__ A,
                                                const ushort_t* __restrict__ B,
                                                float* __restrict__ C, int M, int N, int K,
                                                int nbx) {
  __shared__ __attribute__((aligned(16))) ushort_t As[64 * 32];
  __shared__ __attribute__((aligned(16))) ushort_t Bs[128 * 32];
  const int per = gridDim.x >> 3;
  const int fl = (blockIdx.x & 7) * per + (blockIdx.x >> 3);
  const int m0 = (fl / nbx) * 64, n0 = (fl % nbx) * 128;
  const int tid = threadIdx.x, w = tid >> 6, lane = tid & 63;
  const int wn = w * 32;
  const int l15 = lane & 15, l4 = lane >> 4;
  f32x4 acc[4][2];
#pragma unroll
  for (int i = 0; i < 4; ++i)
#pragma unroll
    for (int j = 0; j < 2; ++j)
#pragma unroll
      for (int r = 0; r < 4; ++r) acc[i][j][r] = 0.f;

  for (int k0 = 0; k0 < K; k0 += 32) {
    __syncthreads();
    {
      int c = w * 64 + lane;
      const ushort_t* ga = A + (size_t)(m0 + (c >> 2)) * K + k0 + (c & 3) * 8;
      __builtin_amdgcn_global_load_lds((gvoid_t*)ga, (lvoid_t*)(As + w * 512), 16, 0, 0);
#pragma unroll
      for (int r = 0; r < 2; ++r) {
        int c2 = r * 256 + w * 64 + lane;
        const ushort_t* gb = B + (size_t)(n0 + (c2 >> 2)) * K + k0 + (c2 & 3) * 8;
        __builtin_amdgcn_global_load_lds((gvoid_t*)gb, (lvoid_t*)(Bs + r * 2048 + w * 512), 16, 0, 0);
      }
    }
    __syncthreads();
    bf16x8 af[4], bfr[2];
#pragma unroll
    for (int i = 0; i < 4; ++i) af[i] = *(const bf16x8*)&As[(i * 16 + l15) * 32 + l4 * 8];
#pragma unroll
    for (int j = 0; j < 2; ++j) bfr[j] = *(const bf16x8*)&Bs[(wn + j * 16 + l15) * 32 + l4 * 8];
#pragma unroll
    for (int i = 0; i < 4; ++i)
#pragma unroll
      for (int j = 0; j < 2; ++j)
        acc[i][j] = __builtin_amdgcn_mfma_f32_16x16x32_bf16(af[i], bfr[j], acc[i][j], 0, 0, 0);
  }
#pragma unroll
  for (int i = 0; i < 4; ++i)
#pragma unroll
    for (int j = 0; j < 2; ++j)
#pragma unroll
      for (int r = 0; r < 4; ++r)
        C[(size_t)(m0 + i * 16 + l4 * 4 + r) * N + n0 + wn + j * 16 + l15] = acc[i][j][r];
}

// ------------- V transpose: qkv V-part -> VT[bn][d][j] (bf16) -------------
__global__ __launch_bounds__(256) void k_vt(const ushort_t* __restrict__ qkv,
                                            ushort_t* __restrict__ vt) {
  __shared__ uint32 tile[64 * 65];
  const int jt = blockIdx.x, bn = blockIdx.y, b = bn & 1, n = bn >> 1;
  const int tid = threadIdx.x;
  const int j0 = jt * 64;
#pragma unroll
  for (int rr = 0; rr < 2; ++rr) {
    int lin = rr * 2048 + tid * 8;
    int j = lin >> 6, d0 = lin & 63;
    u16x8 v = *(const u16x8*)(qkv + (size_t)(j0 + j) * 6144 + b * 3072 + 2048 + n * 64 + d0);
#pragma unroll
    for (int e = 0; e < 8; ++e) tile[j * 65 + d0 + e] = v[e];
  }
  __syncthreads();
#pragma unroll
  for (int rr = 0; rr < 2; ++rr) {
    int lin = rr * 2048 + tid * 8;
    int d = lin >> 6, jj = lin & 63;
    u16x8 o;
#pragma unroll
    for (int e = 0; e < 8; ++e) o[e] = (ushort_t)tile[(jj + e) * 65 + d];
    *(u16x8*)(vt + ((size_t)bn * 64 + d) * 2048 + j0 + jj) = o;
  }
}

// ------------- staging: global_load_lds with pre-swizzled source -------------
// LDS [64 rows][8 slots x 8 shorts]; LDS[row][s] = src[row][s ^ g(row)],
// g(row) = (row&7) ^ ((row>>3)&7).
__device__ __forceinline__ void stage_k(const ushort_t* __restrict__ qkv, ushort_t* kw,
                                        int j0, int b, int n, int w, int lane) {
#pragma unroll
  for (int r = 0; r < 2; ++r) {
    int jb_ = w * 16 + r * 8;
    int jb8 = w * 2 + r;
    const ushort_t* ksrc = qkv + (size_t)(j0 + jb_ + (lane >> 3)) * 6144 + b * 3072 + n * 64 + 1024
                           + ((((lane & 7) ^ (lane >> 3) ^ jb8) & 7) << 3);
    __builtin_amdgcn_global_load_lds((gvoid_t*)ksrc, (lvoid_t*)(kw + jb_ * 64), 16, 0, 0);
  }
}
__device__ __forceinline__ void stage_vt(const ushort_t* __restrict__ vt, ushort_t* vw,
                                         int j0, int bn, int w, int lane) {
#pragma unroll
  for (int r = 0; r < 2; ++r) {
    int db_ = w * 16 + r * 8;
    int jb8 = w * 2 + r;
    const ushort_t* vsrc = vt + ((size_t)bn * 64 + db_ + (lane >> 3)) * 2048 + j0
                           + ((((lane & 7) ^ (lane >> 3) ^ jb8) & 7) << 3);
    __builtin_amdgcn_global_load_lds((gvoid_t*)vsrc, (lvoid_t*)(vw + db_ * 64), 16, 0, 0);
  }
}

// ------------- flash attention, split-KV across blocks (z = KV half) -------------
// Fixed-max softmax: P = exp(s) (Q prescaled), l via per-lane VALU tree.
// REGISTER-LEAN (jb-split, no lacc). __launch_bounds__(256,4): total regs <= 128
// -> 4 waves/SIMD residency (m69 ladder), grid provides 4 blocks/CU.
__global__ __launch_bounds__(256, 4) void k_attn(const ushort_t* __restrict__ qkv,
                                                 const ushort_t* __restrict__ vt,
                                                 ushort_t* o0, ushort_t* o1,
                                                 float* __restrict__ l0,
                                                 float* __restrict__ l1) {
  __shared__ __attribute__((aligned(16))) ushort_t Ks[2][4096];
  __shared__ __attribute__((aligned(16))) ushort_t VTs[2][4096];
  const int bn = blockIdx.y, b = bn & 1, n = bn >> 1, z = blockIdx.z;
  const int tid = threadIdx.x, w = tid >> 6, lane = tid & 63;
  const int l31 = lane & 31, h = lane >> 5;
  const int qrow = blockIdx.x * 128 + w * 32 + l31;
  const size_t qoff = (size_t)qrow * 6144 + b * 3072 + n * 64;
  const float CEXP = 0.18033688011113723f;  // 0.125 * log2(e)
  bf16x8 qf[4];
#pragma unroll
  for (int ks = 0; ks < 4; ++ks) {
    u16x8 qv = *(const u16x8*)(qkv + qoff + ks * 16 + h * 8);
    union { u16x8 u; bf16x8 v; } cu;
#pragma unroll
    for (int e = 0; e < 8; ++e) cu.u[e] = f2bf(bf2f(qv[e]) * CEXP);
    qf[ks] = cu.v;
  }
  const int fA = (l31 & 7) ^ (l31 >> 3);
  const int fB = fA ^ 4;

  const int t0 = z * 16;  // this block's first KV tile
  stage_k(qkv, Ks[0], t0 * 64, b, n, w, lane);
  stage_vt(vt, VTs[0], t0 * 64, bn, w, lane);
  __syncthreads();

  f32x16 oacc[2];
#pragma unroll
  for (int r = 0; r < 16; ++r) { oacc[0][r] = 0.f; oacc[1][r] = 0.f; }
  float lsum = 0.f;

  for (int t = 0; t < 16; ++t) {
    const ushort_t* Kb = Ks[t & 1];
    const ushort_t* Vb = VTs[t & 1];
    if (t < 15) {
      stage_k(qkv, Ks[(t + 1) & 1], (t0 + t + 1) * 64, b, n, w, lane);
      stage_vt(vt, VTs[(t + 1) & 1], (t0 + t + 1) * 64, bn, w, lane);
    }
    // jb-split: QK(j-half) -> exp -> PV(2 slots) -> l-tree, sv reused per half
#pragma unroll
    for (int jb = 0; jb < 2; ++jb) {
      f32x16 sv;
#pragma unroll
      for (int r = 0; r < 16; ++r) sv[r] = 0.f;
      const int rb = (jb * 32 + l31) * 64;
      const int fj = jb ? fB : fA;
      __builtin_amdgcn_s_setprio(1);
#pragma unroll
      for (int ks = 0; ks < 4; ++ks) {
        bf16x8 kf = *(const bf16x8*)&Kb[rb + ((((ks << 1) | h) ^ fj) << 3)];
        sv = __builtin_amdgcn_mfma_f32_32x32x16_bf16(kf, qf[ks], sv, 0, 0, 0);
      }
      __builtin_amdgcn_s_setprio(0);
#pragma unroll
      for (int r = 0; r < 16; ++r) sv[r] = __builtin_amdgcn_exp2f(sv[r]);
      // PV slots for this j-half
#pragma unroll
      for (int ks2 = 0; ks2 < 2; ++ks2) {
        const int q0 = ks2 * 2;
        uint32 X0, X1, Y0, Y1;
        asm volatile("v_cvt_pk_bf16_f32 %0, %1, %2" : "=v"(X0) : "v"(sv[q0 * 4 + 0]), "v"(sv[q0 * 4 + 1]));
        asm volatile("v_cvt_pk_bf16_f32 %0, %1, %2" : "=v"(X1) : "v"(sv[q0 * 4 + 2]), "v"(sv[q0 * 4 + 3]));
        asm volatile("v_cvt_pk_bf16_f32 %0, %1, %2" : "=v"(Y0) : "v"(sv[(q0 + 1) * 4 + 0]), "v"(sv[(q0 + 1) * 4 + 1]));
        asm volatile("v_cvt_pk_bf16_f32 %0, %1, %2" : "=v"(Y1) : "v"(sv[(q0 + 1) * 4 + 2]), "v"(sv[(q0 + 1) * 4 + 3]));
        asm volatile("v_permlane32_swap_b32 %0, %1" : "+v"(X0), "+v"(Y0));
        asm volatile("v_permlane32_swap_b32 %0, %1" : "+v"(X1), "+v"(Y1));
        union { u32x4 u; bf16x8 v; } pf;
        pf.u[0] = X0; pf.u[1] = X1; pf.u[2] = Y0; pf.u[3] = Y1;
        const int c = ((jb * 2 + ks2) << 1) | h;
        bf16x8 vf0 = *(const bf16x8*)&Vb[l31 * 64 + ((c ^ fA) << 3)];
        bf16x8 vf1 = *(const bf16x8*)&Vb[(32 + l31) * 64 + ((c ^ fB) << 3)];
        __builtin_amdgcn_s_setprio(1);
        oacc[0] = __builtin_amdgcn_mfma_f32_32x32x16_bf16(vf0, pf.v, oacc[0], 0, 0, 0);
        oacc[1] = __builtin_amdgcn_mfma_f32_32x32x16_bf16(vf1, pf.v, oacc[1], 0, 0, 0);
        __builtin_amdgcn_s_setprio(0);
      }
      // l tree for this half (off critical path)
      float ls[8];
#pragma unroll
      for (int r = 0; r < 8; ++r) ls[r] = sv[r] + sv[r + 8];
#pragma unroll
      for (int st = 4; st >= 1; st >>= 1)
#pragma unroll
        for (int r = 0; r < st; ++r) ls[r] += ls[r + st];
      lsum += ls[0];
    }
    if (t < 15) __syncthreads();
  }
  const float l_run = lsum + __shfl_xor(lsum, 32);

  // ---- write RAW partials (bf16 O, fp32 l) ----
  ushort_t* op = (z == 0) ? (o0 + (size_t)qrow * 2048 + b * 1024 + n * 64)
                          : (o1 + (size_t)qrow * 6144 + b * 3072 + 2048 + n * 64);
#pragma unroll
  for (int db = 0; db < 2; ++db)
#pragma unroll
    for (int qq = 0; qq < 4; ++qq) {
      u16x4 st;
#pragma unroll
      for (int m = 0; m < 4; ++m) st[m] = f2bf(oacc[db][qq * 4 + m]);
      *(u16x4*)(op + db * 32 + qq * 8 + h * 4) = st;
    }
  if (h == 0) {
    float* lp = (z == 0) ? l0 : l1;
    lp[qrow * 32 + bn] = l_run;
  }
}

// ------------- combine halves + memory retrieval + gated injection -------------
__global__ __launch_bounds__(256) void k_gate2(const ushort_t* __restrict__ qkv,
                                               const ushort_t* __restrict__ o0,
                                               const float* __restrict__ l0,
                                               const float* __restrict__ l1,
                                               const float* __restrict__ mem,
                                               const float* __restrict__ mnorm,
                                               const float* __restrict__ gbeta,
                                               ushort_t* __restrict__ inj) {
  const int bn = blockIdx.y, b = bn & 1, n = bn >> 1;
  const int tid = threadIdx.x, w = tid >> 6, lane = tid & 63;
  const int l31 = lane & 31, h = lane >> 5;
  const int qrow = blockIdx.x * 128 + w * 32 + l31;
  const size_t qoff = (size_t)qrow * 6144 + b * 3072 + n * 64;

  float den = 0.f;
  bf16x8 cqf[4];
  const float* nrm = mnorm + (size_t)(b * NHEAD + n) * 64;
#pragma unroll
  for (int ks = 0; ks < 4; ++ks) {
    u16x8 qv = *(const u16x8*)(qkv + qoff + ks * 16 + h * 8);
    union { u16x8 u; bf16x8 v; } cu;
#pragma unroll
    for (int e = 0; e < 8; ++e) {
      float x = bf2f(qv[e]);
      float c = (x > 0.f) ? (x + 1.f) : __builtin_amdgcn_exp2f(x * 1.4426950408889634f);
      cu.u[e] = f2bf(c);
      den += c * nrm[ks * 16 + h * 8 + e];
    }
    cqf[ks] = cu.v;
  }
  den += __shfl_xor(den, 32);

  const float* mb = mem + (size_t)(b * NHEAD + n) * 4096;
  f32x16 accv[2];
#pragma unroll
  for (int r = 0; r < 16; ++r) { accv[0][r] = 0.f; accv[1][r] = 0.f; }
#pragma unroll
  for (int db = 0; db < 2; ++db)
#pragma unroll
    for (int ks = 0; ks < 4; ++ks) {
      union { u16x8 u; bf16x8 v; } af;
#pragma unroll
      for (int e = 0; e < 8; ++e)
        af.u[e] = f2bf(mb[(size_t)(ks * 16 + h * 8 + e) * 64 + db * 32 + l31]);
      accv[db] = __builtin_amdgcn_mfma_f32_32x32x16_bf16(af.v, cqf[ks], accv[db], 0, 0, 0);
    }

  const float lsum = l0[qrow * 32 + bn] + l1[qrow * 32 + bn];
  float g = 1.f / (1.f + expf(-gbeta[0]));
  float rden = 1.f / den, invl = 1.f / lsum;
  const ushort_t* p0 = o0 + (size_t)qrow * 2048 + b * 1024 + n * 64;
  const ushort_t* p1 = qkv + (size_t)qrow * 6144 + b * 3072 + 2048 + n * 64;
  ushort_t* op = inj + (size_t)qrow * 2048 + b * 1024 + n * 64;
#pragma unroll
  for (int db = 0; db < 2; ++db)
#pragma unroll
    for (int qq = 0; qq < 4; ++qq) {
      const int off = db * 32 + qq * 8 + h * 4;
      u16x4 a0 = *(const u16x4*)(p0 + off);
      u16x4 a1 = *(const u16x4*)(p1 + off);
      u16x4 st;
#pragma unroll
      for (int m = 0; m < 4; ++m) {
        float av = (bf2f(a0[m]) + bf2f(a1[m])) * invl;
        float content = accv[db][qq * 4 + m] * rden;
        st[m] = f2bf(g * content + (1.f - g) * av);
      }
      *(u16x4*)(op + off) = st;
    }
}

// ------------- y = h + attn_out; LayerNorm(D=1024) -------------
__global__ __launch_bounds__(256) void k_ln(const float* __restrict__ h,
                                            const float* __restrict__ ao,
                                            const float* __restrict__ gam,
                                            const float* __restrict__ bet,
                                            float* __restrict__ out) {
  const int m = blockIdx.x, t = threadIdx.x;
  const int lane = t & 63, w = t >> 6;
  __shared__ float redS[4], redQ[4];
  const size_t base = (size_t)m * 1024;
  float4 hv = ((const float4*)(h + base))[t];
  float4 avv = ((const float4*)(ao + base))[t];
  float y0 = hv.x + avv.x, y1 = hv.y + avv.y, y2 = hv.z + avv.z, y3 = hv.w + avv.w;
  float s = y0 + y1 + y2 + y3;
  float sq = y0 * y0 + y1 * y1 + y2 * y2 + y3 * y3;
#pragma unroll
  for (int mk = 32; mk >= 1; mk >>= 1) { s += __shfl_xor(s, mk); sq += __shfl_xor(sq, mk); }
  if (lane == 0) { redS[w] = s; redQ[w] = sq; }
  __syncthreads();
  float Ssum = redS[0] + redS[1] + redS[2] + redS[3];
  float Qsum = redQ[0] + redQ[1] + redQ[2] + redQ[3];
  float mu = Ssum * (1.f / 1024.f);
  float var = Qsum * (1.f / 1024.f) - mu * mu;
  float rstd = rsqrtf(var + 1e-5f);
  float4 g = ((const float4*)gam)[t];
  float4 bt = ((const float4*)bet)[t];
  float4 o;
  o.x = (y0 - mu) * rstd * g.x + bt.x;
  o.y = (y1 - mu) * rstd * g.y + bt.y;
  o.z = (y2 - mu) * rstd * g.z + bt.z;
  o.w = (y3 - mu) * rstd * g.w + bt.w;
  ((float4*)(out + base))[t] = o;
}

extern "C" void kernel_launch(void* const* d_in, const int* in_sizes, int n_in,
                              void* d_out, int out_size, void* d_ws, size_t ws_size,
                              hipStream_t stream) {
  const float* h = (const float*)d_in[0];
  const float* Wq = (const float*)d_in[1];
  const float* Wkv = (const float*)d_in[2];
  const float* Wo = (const float*)d_in[3];
  const float* gam = (const float*)d_in[4];
  const float* bet = (const float*)d_in[5];
  const float* mem = (const float*)d_in[6];
  const float* mnorm = (const float*)d_in[7];
  const float* gbeta = (const float*)d_in[8];
  float* out = (float*)d_out;

  char* ws = (char*)d_ws;
  // [0,8M)   hb  (gemm1 A)      -> O0 partials (attn z=0)
  // [8M,14M) wT  (gemm1 B)      -> l0 at [8M,+256K), l1 at [8M+256K,+256K)
  // [14M,16M) woT (gemm2 B)
  // [16M,40M) qkv (V-slots -> O1 partials during attn) -> ao fp32 after combine
  // [40M,48M) vt  (attn V^T)    -> inj (combine output, gemm2 A)
  ushort_t* hb  = (ushort_t*)(ws);
  ushort_t* wT  = (ushort_t*)(ws + (size_t)(8u << 20));
  ushort_t* woT = (ushort_t*)(ws + (size_t)(14u << 20));
  ushort_t* qkv = (ushort_t*)(ws + (size_t)(16u << 20));
  float*    ao  = (float*)   (ws + (size_t)(16u << 20));  // alias qkv (dead by then)
  ushort_t* vtb = (ushort_t*)(ws + (size_t)(40u << 20));
  ushort_t* o0  = hb;                                     // alias hb (dead by then)
  float*    l0  = (float*)(ws + (size_t)(8u << 20));      // alias wT (dead by then)
  float*    l1  = (float*)(ws + (size_t)(8u << 20) + (1u << 18));
  ushort_t* inj = vtb;                                    // alias vt (dead by then)

  k_cvt_h<<<4096, 256, 0, stream>>>(h, hb, 1048576);
  k_cvt_wT3<<<dim3(64, 32, 3), 256, 0, stream>>>(Wq, Wkv, Wo, wT, woT);
  k_gemm_bt<1><<<768, 256, 0, stream>>>(hb, wT, (void*)qkv, 4096, 3072, 1024, 24);
  k_vt<<<dim3(32, 32), 256, 0, stream>>>(qkv, vtb);
  k_attn<<<dim3(16, 32, 2), 256, 0, stream>>>(qkv, vtb, o0, qkv, l0, l1);
  k_gate2<<<dim3(16, 32), 256, 0, stream>>>(qkv, o0, l0, l1, mem, mnorm, gbeta, inj);
  k_gemm64<<<512, 256, 0, stream>>>(inj, woT, ao, 4096, 1024, 1024, 8);
  k_ln<<<4096, 256, 0, stream>>>(h, ao, gam, bet, out);
}

// Round 12
// 144.369 us; speedup vs baseline: 1.0417x; 1.0417x over previous
//
#include <hip/hip_runtime.h>

// InfiniAttn forward on gfx950.
// cvt h->bf16 | transpose W->bf16 (merged) | GEMM qkv (BK=64, swizzled LDS) |
// V-transpose | flash attn SPLIT-KV across blocks (fixed-max, register-lean,
// loop-carried staging pointers) | combine+mem-gate | GEMM out 64x128 | +h,LN.

typedef unsigned short ushort_t;
typedef unsigned int uint32;

typedef __bf16 bf16x8 __attribute__((ext_vector_type(8)));
typedef float f32x4 __attribute__((ext_vector_type(4)));
typedef float f32x16 __attribute__((ext_vector_type(16)));
typedef unsigned short u16x8 __attribute__((ext_vector_type(8)));
typedef unsigned short u16x4 __attribute__((ext_vector_type(4)));
typedef unsigned int u32x4 __attribute__((ext_vector_type(4)));

typedef const __attribute__((address_space(1))) void gvoid_t;
typedef __attribute__((address_space(3))) void lvoid_t;

#define S_LEN 2048
#define BATCH 2
#define NHEAD 16

__device__ __forceinline__ ushort_t f2bf(float x) {
  union { float f; unsigned u; } c; c.f = x;
  unsigned r = (c.u + 0x7FFFu + ((c.u >> 16) & 1u)) >> 16;
  return (ushort_t)r;
}
__device__ __forceinline__ float bf2f(ushort_t v) {
  union { unsigned u; float f; } c; c.u = ((unsigned)v) << 16;
  return c.f;
}

// ---------------- dtype convert: h (fp32) -> bf16 ----------------
__global__ __launch_bounds__(256) void k_cvt_h(const float* __restrict__ src,
                                               ushort_t* __restrict__ dst, int n4) {
  int idx = blockIdx.x * 256 + threadIdx.x;
  if (idx >= n4) return;
  float4 v = ((const float4*)src)[idx];
  u16x4 o; o[0] = f2bf(v.x); o[1] = f2bf(v.y); o[2] = f2bf(v.z); o[3] = f2bf(v.w);
  ((u16x4*)dst)[idx] = o;
}

// ------------- transpose-convert (merged): W[K][N] fp32 -> WT[N][K] bf16 -------------
__global__ __launch_bounds__(256) void k_cvt_wT3(const float* __restrict__ Wq,
                                                 const float* __restrict__ Wkv,
                                                 const float* __restrict__ Wo,
                                                 ushort_t* __restrict__ wT,
                                                 ushort_t* __restrict__ woT) {
  const int z = blockIdx.z;
  const float* W;
  ushort_t* WT;
  int N;
  if (z == 0)      { W = Wq;  WT = wT;                          N = 1024; }
  else if (z == 1) { W = Wkv; WT = wT + (size_t)1024 * 1024;    N = 2048; }
  else             { W = Wo;  WT = woT;                         N = 1024; }
  const int K = 1024;
  if (blockIdx.x * 32 >= N) return;
  __shared__ float tile[32][33];
  const int n0 = blockIdx.x * 32, k0 = blockIdx.y * 32;
  const int tx = threadIdx.x & 31, ty = threadIdx.x >> 5;
#pragma unroll
  for (int r = 0; r < 32; r += 8)
    tile[ty + r][tx] = W[(size_t)(k0 + ty + r) * N + n0 + tx];
  __syncthreads();
#pragma unroll
  for (int r = 0; r < 32; r += 8)
    WT[(size_t)(n0 + ty + r) * K + k0 + tx] = f2bf(tile[tx][ty + r]);
}

// ------------- GEMM 128x128, BK=64: C = A[M][K](bf16) * B[N][K]^T(bf16) -------------
// LDS [128 rows][8 slots x 8 shorts]; LDS[row][s] = src[row][s ^ (row&7)]
// (pre-swizzled global source, attn-R7-verified conflict-free pattern).
template <int OUT_BF16>
__global__ __launch_bounds__(256) void k_gemm_bt(const ushort_t* __restrict__ A,
                                                 const ushort_t* __restrict__ B,
                                                 void* __restrict__ Cv, int M, int N, int K,
                                                 int nbx) {
  __shared__ __attribute__((aligned(16))) ushort_t As[128 * 64];
  __shared__ __attribute__((aligned(16))) ushort_t Bs[128 * 64];
  const int per = gridDim.x >> 3;  // grid % 8 == 0
  const int fl = (blockIdx.x & 7) * per + (blockIdx.x >> 3);
  const int m0 = (fl / nbx) * 128, n0 = (fl % nbx) * 128;
  const int tid = threadIdx.x, w = tid >> 6, lane = tid & 63;
  const int wm = (w >> 1) * 64, wn = (w & 1) * 64;
  const int l15 = lane & 15, l4 = lane >> 4;
  const int sw = ((lane & 7) ^ (lane >> 3)) << 3;  // source col pre-swizzle (shorts)
  f32x4 acc[4][4];
#pragma unroll
  for (int i = 0; i < 4; ++i)
#pragma unroll
    for (int j = 0; j < 4; ++j)
#pragma unroll
      for (int r = 0; r < 4; ++r) acc[i][j][r] = 0.f;

  for (int k0 = 0; k0 < K; k0 += 64) {
    __syncthreads();
#pragma unroll
    for (int r = 0; r < 4; ++r) {
      int rowb = r * 32 + w * 8;  // rows rowb..rowb+7 this call; rowb % 8 == 0
      const ushort_t* ga = A + (size_t)(m0 + rowb + (lane >> 3)) * K + k0 + sw;
      const ushort_t* gb = B + (size_t)(n0 + rowb + (lane >> 3)) * K + k0 + sw;
      __builtin_amdgcn_global_load_lds((gvoid_t*)ga, (lvoid_t*)(As + rowb * 64), 16, 0, 0);
      __builtin_amdgcn_global_load_lds((gvoid_t*)gb, (lvoid_t*)(Bs + rowb * 64), 16, 0, 0);
    }
    __syncthreads();
#pragma unroll
    for (int kk = 0; kk < 2; ++kk) {
      bf16x8 af[4], bfr[4];
#pragma unroll
      for (int i = 0; i < 4; ++i) {
        int row = wm + i * 16 + l15;
        af[i] = *(const bf16x8*)&As[row * 64 + (((kk * 4 + l4) ^ (row & 7)) << 3)];
      }
#pragma unroll
      for (int j = 0; j < 4; ++j) {
        int row = wn + j * 16 + l15;
        bfr[j] = *(const bf16x8*)&Bs[row * 64 + (((kk * 4 + l4) ^ (row & 7)) << 3)];
      }
#pragma unroll
      for (int i = 0; i < 4; ++i)
#pragma unroll
        for (int j = 0; j < 4; ++j)
          acc[i][j] = __builtin_amdgcn_mfma_f32_16x16x32_bf16(af[i], bfr[j], acc[i][j], 0, 0, 0);
    }
  }
#pragma unroll
  for (int i = 0; i < 4; ++i)
#pragma unroll
    for (int j = 0; j < 4; ++j)
#pragma unroll
      for (int r = 0; r < 4; ++r) {
        int row = m0 + wm + i * 16 + l4 * 4 + r;
        int col = n0 + wn + j * 16 + l15;
        if (OUT_BF16)
          ((ushort_t*)Cv)[(size_t)row * N + col] = f2bf(acc[i][j][r]);
        else
          ((float*)Cv)[(size_t)row * N + col] = acc[i][j][r];
      }
}

// ------------- GEMM 64x128 tiles (M=4096,N=1024: 512 blocks = 2/CU) -------------
__global__ __launch_bounds__(256) void k_gemm64(const ushort_t* __restrict__ A,
                                                const ushort_t* __restrict__ B,
                                                float* __restrict__ C, int M, int N, int K,
                                                int nbx) {
  __shared__ __attribute__((aligned(16))) ushort_t As[64 * 32];
  __shared__ __attribute__((aligned(16))) ushort_t Bs[128 * 32];
  const int per = gridDim.x >> 3;
  const int fl = (blockIdx.x & 7) * per + (blockIdx.x >> 3);
  const int m0 = (fl / nbx) * 64, n0 = (fl % nbx) * 128;
  const int tid = threadIdx.x, w = tid >> 6, lane = tid & 63;
  const int wn = w * 32;
  const int l15 = lane & 15, l4 = lane >> 4;
  f32x4 acc[4][2];
#pragma unroll
  for (int i = 0; i < 4; ++i)
#pragma unroll
    for (int j = 0; j < 2; ++j)
#pragma unroll
      for (int r = 0; r < 4; ++r) acc[i][j][r] = 0.f;

  for (int k0 = 0; k0 < K; k0 += 32) {
    __syncthreads();
    {
      int c = w * 64 + lane;
      const ushort_t* ga = A + (size_t)(m0 + (c >> 2)) * K + k0 + (c & 3) * 8;
      __builtin_amdgcn_global_load_lds((gvoid_t*)ga, (lvoid_t*)(As + w * 512), 16, 0, 0);
#pragma unroll
      for (int r = 0; r < 2; ++r) {
        int c2 = r * 256 + w * 64 + lane;
        const ushort_t* gb = B + (size_t)(n0 + (c2 >> 2)) * K + k0 + (c2 & 3) * 8;
        __builtin_amdgcn_global_load_lds((gvoid_t*)gb, (lvoid_t*)(Bs + r * 2048 + w * 512), 16, 0, 0);
      }
    }
    __syncthreads();
    bf16x8 af[4], bfr[2];
#pragma unroll
    for (int i = 0; i < 4; ++i) af[i] = *(const bf16x8*)&As[(i * 16 + l15) * 32 + l4 * 8];
#pragma unroll
    for (int j = 0; j < 2; ++j) bfr[j] = *(const bf16x8*)&Bs[(wn + j * 16 + l15) * 32 + l4 * 8];
#pragma unroll
    for (int i = 0; i < 4; ++i)
#pragma unroll
      for (int j = 0; j < 2; ++j)
        acc[i][j] = __builtin_amdgcn_mfma_f32_16x16x32_bf16(af[i], bfr[j], acc[i][j], 0, 0, 0);
  }
#pragma unroll
  for (int i = 0; i < 4; ++i)
#pragma unroll
    for (int j = 0; j < 2; ++j)
#pragma unroll
      for (int r = 0; r < 4; ++r)
        C[(size_t)(m0 + i * 16 + l4 * 4 + r) * N + n0 + wn + j * 16 + l15] = acc[i][j][r];
}

// ------------- V transpose: qkv V-part -> VT[bn][d][j] (bf16) -------------
__global__ __launch_bounds__(256) void k_vt(const ushort_t* __restrict__ qkv,
                                            ushort_t* __restrict__ vt) {
  __shared__ uint32 tile[64 * 65];
  const int jt = blockIdx.x, bn = blockIdx.y, b = bn & 1, n = bn >> 1;
  const int tid = threadIdx.x;
  const int j0 = jt * 64;
#pragma unroll
  for (int rr = 0; rr < 2; ++rr) {
    int lin = rr * 2048 + tid * 8;
    int j = lin >> 6, d0 = lin & 63;
    u16x8 v = *(const u16x8*)(qkv + (size_t)(j0 + j) * 6144 + b * 3072 + 2048 + n * 64 + d0);
#pragma unroll
    for (int e = 0; e < 8; ++e) tile[j * 65 + d0 + e] = v[e];
  }
  __syncthreads();
#pragma unroll
  for (int rr = 0; rr < 2; ++rr) {
    int lin = rr * 2048 + tid * 8;
    int d = lin >> 6, jj = lin & 63;
    u16x8 o;
#pragma unroll
    for (int e = 0; e < 8; ++e) o[e] = (ushort_t)tile[(jj + e) * 65 + d];
    *(u16x8*)(vt + ((size_t)bn * 64 + d) * 2048 + j0 + jj) = o;
  }
}

// ------------- flash attention, split-KV across blocks (z = KV half) -------------
// Fixed-max softmax: P = exp(s) (Q prescaled), l via per-lane VALU tree.
// Register-lean (jb-split). Staging via LOOP-CARRIED pointers (constant-stride
// advance replaces per-tile 64-bit address mults). LDS[row][s] = src[row][s^g(row)],
// g(row) = (row&7)^((row>>3)&7).
__global__ __launch_bounds__(256, 4) void k_attn(const ushort_t* __restrict__ qkv,
                                                 const ushort_t* __restrict__ vt,
                                                 ushort_t* o0, ushort_t* o1,
                                                 float* __restrict__ l0,
                                                 float* __restrict__ l1) {
  __shared__ __attribute__((aligned(16))) ushort_t Ks[2][4096];
  __shared__ __attribute__((aligned(16))) ushort_t VTs[2][4096];
  const int bn = blockIdx.y, b = bn & 1, n = bn >> 1, z = blockIdx.z;
  const int tid = threadIdx.x, w = tid >> 6, lane = tid & 63;
  const int l31 = lane & 31, h = lane >> 5;
  const int qrow = blockIdx.x * 128 + w * 32 + l31;
  const size_t qoff = (size_t)qrow * 6144 + b * 3072 + n * 64;
  const float CEXP = 0.18033688011113723f;  // 0.125 * log2(e)
  bf16x8 qf[4];
#pragma unroll
  for (int ks = 0; ks < 4; ++ks) {
    u16x8 qv = *(const u16x8*)(qkv + qoff + ks * 16 + h * 8);
    union { u16x8 u; bf16x8 v; } cu;
#pragma unroll
    for (int e = 0; e < 8; ++e) cu.u[e] = f2bf(bf2f(qv[e]) * CEXP);
    qf[ks] = cu.v;
  }
  const int fA = (l31 & 7) ^ (l31 >> 3);
  const int fB = fA ^ 4;

  const int t0 = z * 16;  // this block's first KV tile
  // loop-carried staging pointers (r = 0: rows w*16.., r = 1: rows w*16+8..)
  const int sw0 = (((lane & 7) ^ (lane >> 3) ^ (w * 2)) & 7) << 3;
  const int sw1 = (((lane & 7) ^ (lane >> 3) ^ (w * 2 + 1)) & 7) << 3;
  const ushort_t* kp0 = qkv + (size_t)(t0 * 64 + w * 16 + (lane >> 3)) * 6144 + b * 3072 + n * 64 + 1024 + sw0;
  const ushort_t* kp1 = qkv + (size_t)(t0 * 64 + w * 16 + 8 + (lane >> 3)) * 6144 + b * 3072 + n * 64 + 1024 + sw1;
  const ushort_t* vp0 = vt + ((size_t)bn * 64 + w * 16 + (lane >> 3)) * 2048 + t0 * 64 + sw0;
  const ushort_t* vp1 = vt + ((size_t)bn * 64 + w * 16 + 8 + (lane >> 3)) * 2048 + t0 * 64 + sw1;
  const size_t KSTRIDE = (size_t)64 * 6144;  // advance one KV tile

  // ---- prologue: stage tile t0 into buffer 0 ----
  __builtin_amdgcn_global_load_lds((gvoid_t*)kp0, (lvoid_t*)(Ks[0] + (w * 16) * 64), 16, 0, 0);
  __builtin_amdgcn_global_load_lds((gvoid_t*)kp1, (lvoid_t*)(Ks[0] + (w * 16 + 8) * 64), 16, 0, 0);
  __builtin_amdgcn_global_load_lds((gvoid_t*)vp0, (lvoid_t*)(VTs[0] + (w * 16) * 64), 16, 0, 0);
  __builtin_amdgcn_global_load_lds((gvoid_t*)vp1, (lvoid_t*)(VTs[0] + (w * 16 + 8) * 64), 16, 0, 0);
  kp0 += KSTRIDE; kp1 += KSTRIDE; vp0 += 64; vp1 += 64;
  __syncthreads();

  f32x16 oacc[2];
#pragma unroll
  for (int r = 0; r < 16; ++r) { oacc[0][r] = 0.f; oacc[1][r] = 0.f; }
  float lsum = 0.f;

  for (int t = 0; t < 16; ++t) {
    const ushort_t* Kb = Ks[t & 1];
    const ushort_t* Vb = VTs[t & 1];
    if (t < 15) {
      ushort_t* kw = Ks[(t + 1) & 1];
      ushort_t* vw = VTs[(t + 1) & 1];
      __builtin_amdgcn_global_load_lds((gvoid_t*)kp0, (lvoid_t*)(kw + (w * 16) * 64), 16, 0, 0);
      __builtin_amdgcn_global_load_lds((gvoid_t*)kp1, (lvoid_t*)(kw + (w * 16 + 8) * 64), 16, 0, 0);
      __builtin_amdgcn_global_load_lds((gvoid_t*)vp0, (lvoid_t*)(vw + (w * 16) * 64), 16, 0, 0);
      __builtin_amdgcn_global_load_lds((gvoid_t*)vp1, (lvoid_t*)(vw + (w * 16 + 8) * 64), 16, 0, 0);
      kp0 += KSTRIDE; kp1 += KSTRIDE; vp0 += 64; vp1 += 64;
    }
    // jb-split: QK(j-half) -> exp -> PV(2 slots) -> l-tree, sv reused per half
#pragma unroll
    for (int jb = 0; jb < 2; ++jb) {
      f32x16 sv;
#pragma unroll
      for (int r = 0; r < 16; ++r) sv[r] = 0.f;
      const int rb = (jb * 32 + l31) * 64;
      const int fj = jb ? fB : fA;
      __builtin_amdgcn_s_setprio(1);
#pragma unroll
      for (int ks = 0; ks < 4; ++ks) {
        bf16x8 kf = *(const bf16x8*)&Kb[rb + ((((ks << 1) | h) ^ fj) << 3)];
        sv = __builtin_amdgcn_mfma_f32_32x32x16_bf16(kf, qf[ks], sv, 0, 0, 0);
      }
      __builtin_amdgcn_s_setprio(0);
#pragma unroll
      for (int r = 0; r < 16; ++r) sv[r] = __builtin_amdgcn_exp2f(sv[r]);
      // PV slots for this j-half
#pragma unroll
      for (int ks2 = 0; ks2 < 2; ++ks2) {
        const int q0 = ks2 * 2;
        uint32 X0, X1, Y0, Y1;
        asm volatile("v_cvt_pk_bf16_f32 %0, %1, %2" : "=v"(X0) : "v"(sv[q0 * 4 + 0]), "v"(sv[q0 * 4 + 1]));
        asm volatile("v_cvt_pk_bf16_f32 %0, %1, %2" : "=v"(X1) : "v"(sv[q0 * 4 + 2]), "v"(sv[q0 * 4 + 3]));
        asm volatile("v_cvt_pk_bf16_f32 %0, %1, %2" : "=v"(Y0) : "v"(sv[(q0 + 1) * 4 + 0]), "v"(sv[(q0 + 1) * 4 + 1]));
        asm volatile("v_cvt_pk_bf16_f32 %0, %1, %2" : "=v"(Y1) : "v"(sv[(q0 + 1) * 4 + 2]), "v"(sv[(q0 + 1) * 4 + 3]));
        asm volatile("v_permlane32_swap_b32 %0, %1" : "+v"(X0), "+v"(Y0));
        asm volatile("v_permlane32_swap_b32 %0, %1" : "+v"(X1), "+v"(Y1));
        union { u32x4 u; bf16x8 v; } pf;
        pf.u[0] = X0; pf.u[1] = X1; pf.u[2] = Y0; pf.u[3] = Y1;
        const int c = ((jb * 2 + ks2) << 1) | h;
        bf16x8 vf0 = *(const bf16x8*)&Vb[l31 * 64 + ((c ^ fA) << 3)];
        bf16x8 vf1 = *(const bf16x8*)&Vb[(32 + l31) * 64 + ((c ^ fB) << 3)];
        __builtin_amdgcn_s_setprio(1);
        oacc[0] = __builtin_amdgcn_mfma_f32_32x32x16_bf16(vf0, pf.v, oacc[0], 0, 0, 0);
        oacc[1] = __builtin_amdgcn_mfma_f32_32x32x16_bf16(vf1, pf.v, oacc[1], 0, 0, 0);
        __builtin_amdgcn_s_setprio(0);
      }
      // l tree for this half (off critical path)
      float ls[8];
#pragma unroll
      for (int r = 0; r < 8; ++r) ls[r] = sv[r] + sv[r + 8];
#pragma unroll
      for (int st = 4; st >= 1; st >>= 1)
#pragma unroll
        for (int r = 0; r < st; ++r) ls[r] += ls[r + st];
      lsum += ls[0];
    }
    if (t < 15) __syncthreads();
  }
  const float l_run = lsum + __shfl_xor(lsum, 32);

  // ---- write RAW partials (bf16 O, fp32 l) ----
  ushort_t* op = (z == 0) ? (o0 + (size_t)qrow * 2048 + b * 1024 + n * 64)
                          : (o1 + (size_t)qrow * 6144 + b * 3072 + 2048 + n * 64);
#pragma unroll
  for (int db = 0; db < 2; ++db)
#pragma unroll
    for (int qq = 0; qq < 4; ++qq) {
      u16x4 st;
#pragma unroll
      for (int m = 0; m < 4; ++m) st[m] = f2bf(oacc[db][qq * 4 + m]);
      *(u16x4*)(op + db * 32 + qq * 8 + h * 4) = st;
    }
  if (h == 0) {
    float* lp = (z == 0) ? l0 : l1;
    lp[qrow * 32 + bn] = l_run;
  }
}

// ------------- combine halves + memory retrieval + gated injection -------------
__global__ __launch_bounds__(256) void k_gate2(const ushort_t* __restrict__ qkv,
                                               const ushort_t* __restrict__ o0,
                                               const float* __restrict__ l0,
                                               const float* __restrict__ l1,
                                               const float* __restrict__ mem,
                                               const float* __restrict__ mnorm,
                                               const float* __restrict__ gbeta,
                                               ushort_t* __restrict__ inj) {
  const int bn = blockIdx.y, b = bn & 1, n = bn >> 1;
  const int tid = threadIdx.x, w = tid >> 6, lane = tid & 63;
  const int l31 = lane & 31, h = lane >> 5;
  const int qrow = blockIdx.x * 128 + w * 32 + l31;
  const size_t qoff = (size_t)qrow * 6144 + b * 3072 + n * 64;

  float den = 0.f;
  bf16x8 cqf[4];
  const float* nrm = mnorm + (size_t)(b * NHEAD + n) * 64;
#pragma unroll
  for (int ks = 0; ks < 4; ++ks) {
    u16x8 qv = *(const u16x8*)(qkv + qoff + ks * 16 + h * 8);
    union { u16x8 u; bf16x8 v; } cu;
#pragma unroll
    for (int e = 0; e < 8; ++e) {
      float x = bf2f(qv[e]);
      float c = (x > 0.f) ? (x + 1.f) : __builtin_amdgcn_exp2f(x * 1.4426950408889634f);
      cu.u[e] = f2bf(c);
      den += c * nrm[ks * 16 + h * 8 + e];
    }
    cqf[ks] = cu.v;
  }
  den += __shfl_xor(den, 32);

  const float* mb = mem + (size_t)(b * NHEAD + n) * 4096;
  f32x16 accv[2];
#pragma unroll
  for (int r = 0; r < 16; ++r) { accv[0][r] = 0.f; accv[1][r] = 0.f; }
#pragma unroll
  for (int db = 0; db < 2; ++db)
#pragma unroll
    for (int ks = 0; ks < 4; ++ks) {
      union { u16x8 u; bf16x8 v; } af;
#pragma unroll
      for (int e = 0; e < 8; ++e)
        af.u[e] = f2bf(mb[(size_t)(ks * 16 + h * 8 + e) * 64 + db * 32 + l31]);
      accv[db] = __builtin_amdgcn_mfma_f32_32x32x16_bf16(af.v, cqf[ks], accv[db], 0, 0, 0);
    }

  const float lsum = l0[qrow * 32 + bn] + l1[qrow * 32 + bn];
  float g = 1.f / (1.f + expf(-gbeta[0]));
  float rden = 1.f / den, invl = 1.f / lsum;
  const ushort_t* p0 = o0 + (size_t)qrow * 2048 + b * 1024 + n * 64;
  const ushort_t* p1 = qkv + (size_t)qrow * 6144 + b * 3072 + 2048 + n * 64;
  ushort_t* op = inj + (size_t)qrow * 2048 + b * 1024 + n * 64;
#pragma unroll
  for (int db = 0; db < 2; ++db)
#pragma unroll
    for (int qq = 0; qq < 4; ++qq) {
      const int off = db * 32 + qq * 8 + h * 4;
      u16x4 a0 = *(const u16x4*)(p0 + off);
      u16x4 a1 = *(const u16x4*)(p1 + off);
      u16x4 st;
#pragma unroll
      for (int m = 0; m < 4; ++m) {
        float av = (bf2f(a0[m]) + bf2f(a1[m])) * invl;
        float content = accv[db][qq * 4 + m] * rden;
        st[m] = f2bf(g * content + (1.f - g) * av);
      }
      *(u16x4*)(op + off) = st;
    }
}

// ------------- y = h + attn_out; LayerNorm(D=1024) -------------
__global__ __launch_bounds__(256) void k_ln(const float* __restrict__ h,
                                            const float* __restrict__ ao,
                                            const float* __restrict__ gam,
                                            const float* __restrict__ bet,
                                            float* __restrict__ out) {
  const int m = blockIdx.x, t = threadIdx.x;
  const int lane = t & 63, w = t >> 6;
  __shared__ float redS[4], redQ[4];
  const size_t base = (size_t)m * 1024;
  float4 hv = ((const float4*)(h + base))[t];
  float4 avv = ((const float4*)(ao + base))[t];
  float y0 = hv.x + avv.x, y1 = hv.y + avv.y, y2 = hv.z + avv.z, y3 = hv.w + avv.w;
  float s = y0 + y1 + y2 + y3;
  float sq = y0 * y0 + y1 * y1 + y2 * y2 + y3 * y3;
#pragma unroll
  for (int mk = 32; mk >= 1; mk >>= 1) { s += __shfl_xor(s, mk); sq += __shfl_xor(sq, mk); }
  if (lane == 0) { redS[w] = s; redQ[w] = sq; }
  __syncthreads();
  float Ssum = redS[0] + redS[1] + redS[2] + redS[3];
  float Qsum = redQ[0] + redQ[1] + redQ[2] + redQ[3];
  float mu = Ssum * (1.f / 1024.f);
  float var = Qsum * (1.f / 1024.f) - mu * mu;
  float rstd = rsqrtf(var + 1e-5f);
  float4 g = ((const float4*)gam)[t];
  float4 bt = ((const float4*)bet)[t];
  float4 o;
  o.x = (y0 - mu) * rstd * g.x + bt.x;
  o.y = (y1 - mu) * rstd * g.y + bt.y;
  o.z = (y2 - mu) * rstd * g.z + bt.z;
  o.w = (y3 - mu) * rstd * g.w + bt.w;
  ((float4*)(out + base))[t] = o;
}

extern "C" void kernel_launch(void* const* d_in, const int* in_sizes, int n_in,
                              void* d_out, int out_size, void* d_ws, size_t ws_size,
                              hipStream_t stream) {
  const float* h = (const float*)d_in[0];
  const float* Wq = (const float*)d_in[1];
  const float* Wkv = (const float*)d_in[2];
  const float* Wo = (const float*)d_in[3];
  const float* gam = (const float*)d_in[4];
  const float* bet = (const float*)d_in[5];
  const float* mem = (const float*)d_in[6];
  const float* mnorm = (const float*)d_in[7];
  const float* gbeta = (const float*)d_in[8];
  float* out = (float*)d_out;

  char* ws = (char*)d_ws;
  // [0,8M)   hb  (gemm1 A)      -> O0 partials (attn z=0)
  // [8M,14M) wT  (gemm1 B)      -> l0 at [8M,+256K), l1 at [8M+256K,+256K)
  // [14M,16M) woT (gemm2 B)
  // [16M,40M) qkv (V-slots -> O1 partials during attn) -> ao fp32 after combine
  // [40M,48M) vt  (attn V^T)    -> inj (combine output, gemm2 A)
  ushort_t* hb  = (ushort_t*)(ws);
  ushort_t* wT  = (ushort_t*)(ws + (size_t)(8u << 20));
  ushort_t* woT = (ushort_t*)(ws + (size_t)(14u << 20));
  ushort_t* qkv = (ushort_t*)(ws + (size_t)(16u << 20));
  float*    ao  = (float*)   (ws + (size_t)(16u << 20));  // alias qkv (dead by then)
  ushort_t* vtb = (ushort_t*)(ws + (size_t)(40u << 20));
  ushort_t* o0  = hb;                                     // alias hb (dead by then)
  float*    l0  = (float*)(ws + (size_t)(8u << 20));      // alias wT (dead by then)
  float*    l1  = (float*)(ws + (size_t)(8u << 20) + (1u << 18));
  ushort_t* inj = vtb;                                    // alias vt (dead by then)

  k_cvt_h<<<4096, 256, 0, stream>>>(h, hb, 1048576);
  k_cvt_wT3<<<dim3(64, 32, 3), 256, 0, stream>>>(Wq, Wkv, Wo, wT, woT);
  k_gemm_bt<1><<<768, 256, 0, stream>>>(hb, wT, (void*)qkv, 4096, 3072, 1024, 24);
  k_vt<<<dim3(32, 32), 256, 0, stream>>>(qkv, vtb);
  k_attn<<<dim3(16, 32, 2), 256, 0, stream>>>(qkv, vtb, o0, qkv, l0, l1);
  k_gate2<<<dim3(16, 32), 256, 0, stream>>>(qkv, o0, l0, l1, mem, mnorm, gbeta, inj);
  k_gemm64<<<512, 256, 0, stream>>>(inj, woT, ao, 4096, 1024, 1024, 8);
  k_ln<<<4096, 256, 0, stream>>>(h, ao, gam, bet, out);
}

// Round 13
// 138.276 us; speedup vs baseline: 1.0876x; 1.0441x over previous
//
#include <hip/hip_runtime.h>

// InfiniAttn forward on gfx950.
// cvt (h + 3×W merged) | GEMM qkv (BK=64, swizzled LDS) | V-transpose | flash attn
// SPLIT-KV across blocks (fixed-max, register-lean) | combine+mem-gate |
// GEMM out (64x128, BK=64 swizzled) | +h,LN.

typedef unsigned short ushort_t;
typedef unsigned int uint32;

typedef __bf16 bf16x8 __attribute__((ext_vector_type(8)));
typedef float f32x4 __attribute__((ext_vector_type(4)));
typedef float f32x16 __attribute__((ext_vector_type(16)));
typedef unsigned short u16x8 __attribute__((ext_vector_type(8)));
typedef unsigned short u16x4 __attribute__((ext_vector_type(4)));
typedef unsigned int u32x4 __attribute__((ext_vector_type(4)));

typedef const __attribute__((address_space(1))) void gvoid_t;
typedef __attribute__((address_space(3))) void lvoid_t;

#define S_LEN 2048
#define BATCH 2
#define NHEAD 16

__device__ __forceinline__ ushort_t f2bf(float x) {
  union { float f; unsigned u; } c; c.f = x;
  unsigned r = (c.u + 0x7FFFu + ((c.u >> 16) & 1u)) >> 16;
  return (ushort_t)r;
}
__device__ __forceinline__ float bf2f(ushort_t v) {
  union { unsigned u; float f; } c; c.u = ((unsigned)v) << 16;
  return c.f;
}

// ------------- merged convert: z<3 -> W transpose-convert; z==3 -> h fp32->bf16 -------------
__global__ __launch_bounds__(256) void k_cvt_all(const float* __restrict__ h,
                                                 const float* __restrict__ Wq,
                                                 const float* __restrict__ Wkv,
                                                 const float* __restrict__ Wo,
                                                 ushort_t* __restrict__ hb,
                                                 ushort_t* __restrict__ wT,
                                                 ushort_t* __restrict__ woT) {
  const int z = blockIdx.z;
  if (z == 3) {  // h convert: 1048576 float4s, 2048 blocks x 256 thr, 2 per thread
    int idx = (blockIdx.y * 64 + blockIdx.x) * 256 + threadIdx.x;
#pragma unroll
    for (int i = 0; i < 2; ++i) {
      int e = idx + i * 524288;
      float4 v = ((const float4*)h)[e];
      u16x4 o; o[0] = f2bf(v.x); o[1] = f2bf(v.y); o[2] = f2bf(v.z); o[3] = f2bf(v.w);
      ((u16x4*)hb)[e] = o;
    }
    return;
  }
  const float* W;
  ushort_t* WT;
  int N;
  if (z == 0)      { W = Wq;  WT = wT;                        N = 1024; }
  else if (z == 1) { W = Wkv; WT = wT + (size_t)1024 * 1024;  N = 2048; }
  else             { W = Wo;  WT = woT;                       N = 1024; }
  const int K = 1024;
  if (blockIdx.x * 32 >= N) return;
  __shared__ float tile[32][33];
  const int n0 = blockIdx.x * 32, k0 = blockIdx.y * 32;
  const int tx = threadIdx.x & 31, ty = threadIdx.x >> 5;
#pragma unroll
  for (int r = 0; r < 32; r += 8)
    tile[ty + r][tx] = W[(size_t)(k0 + ty + r) * N + n0 + tx];
  __syncthreads();
#pragma unroll
  for (int r = 0; r < 32; r += 8)
    WT[(size_t)(n0 + ty + r) * K + k0 + tx] = f2bf(tile[tx][ty + r]);
}

// ------------- GEMM 128x128, BK=64: C = A[M][K](bf16) * B[N][K]^T(bf16) -------------
// LDS [128 rows][8 slots x 8 shorts]; LDS[row][s] = src[row][s ^ (row&7)].
template <int OUT_BF16>
__global__ __launch_bounds__(256) void k_gemm_bt(const ushort_t* __restrict__ A,
                                                 const ushort_t* __restrict__ B,
                                                 void* __restrict__ Cv, int M, int N, int K,
                                                 int nbx) {
  __shared__ __attribute__((aligned(16))) ushort_t As[128 * 64];
  __shared__ __attribute__((aligned(16))) ushort_t Bs[128 * 64];
  const int per = gridDim.x >> 3;  // grid % 8 == 0
  const int fl = (blockIdx.x & 7) * per + (blockIdx.x >> 3);
  const int m0 = (fl / nbx) * 128, n0 = (fl % nbx) * 128;
  const int tid = threadIdx.x, w = tid >> 6, lane = tid & 63;
  const int wm = (w >> 1) * 64, wn = (w & 1) * 64;
  const int l15 = lane & 15, l4 = lane >> 4;
  const int sw = ((lane & 7) ^ (lane >> 3)) << 3;  // source col pre-swizzle (shorts)
  f32x4 acc[4][4];
#pragma unroll
  for (int i = 0; i < 4; ++i)
#pragma unroll
    for (int j = 0; j < 4; ++j)
#pragma unroll
      for (int r = 0; r < 4; ++r) acc[i][j][r] = 0.f;

  for (int k0 = 0; k0 < K; k0 += 64) {
    __syncthreads();
#pragma unroll
    for (int r = 0; r < 4; ++r) {
      int rowb = r * 32 + w * 8;  // rows rowb..rowb+7; rowb % 8 == 0
      const ushort_t* ga = A + (size_t)(m0 + rowb + (lane >> 3)) * K + k0 + sw;
      const ushort_t* gb = B + (size_t)(n0 + rowb + (lane >> 3)) * K + k0 + sw;
      __builtin_amdgcn_global_load_lds((gvoid_t*)ga, (lvoid_t*)(As + rowb * 64), 16, 0, 0);
      __builtin_amdgcn_global_load_lds((gvoid_t*)gb, (lvoid_t*)(Bs + rowb * 64), 16, 0, 0);
    }
    __syncthreads();
#pragma unroll
    for (int kk = 0; kk < 2; ++kk) {
      bf16x8 af[4], bfr[4];
#pragma unroll
      for (int i = 0; i < 4; ++i) {
        int row = wm + i * 16 + l15;
        af[i] = *(const bf16x8*)&As[row * 64 + (((kk * 4 + l4) ^ (row & 7)) << 3)];
      }
#pragma unroll
      for (int j = 0; j < 4; ++j) {
        int row = wn + j * 16 + l15;
        bfr[j] = *(const bf16x8*)&Bs[row * 64 + (((kk * 4 + l4) ^ (row & 7)) << 3)];
      }
#pragma unroll
      for (int i = 0; i < 4; ++i)
#pragma unroll
        for (int j = 0; j < 4; ++j)
          acc[i][j] = __builtin_amdgcn_mfma_f32_16x16x32_bf16(af[i], bfr[j], acc[i][j], 0, 0, 0);
    }
  }
#pragma unroll
  for (int i = 0; i < 4; ++i)
#pragma unroll
    for (int j = 0; j < 4; ++j)
#pragma unroll
      for (int r = 0; r < 4; ++r) {
        int row = m0 + wm + i * 16 + l4 * 4 + r;
        int col = n0 + wn + j * 16 + l15;
        if (OUT_BF16)
          ((ushort_t*)Cv)[(size_t)row * N + col] = f2bf(acc[i][j][r]);
        else
          ((float*)Cv)[(size_t)row * N + col] = acc[i][j][r];
      }
}

// ------------- GEMM 64x128 tiles, BK=64 swizzled (M=4096,N=1024: 512 blocks) -------------
__global__ __launch_bounds__(256) void k_gemm64(const ushort_t* __restrict__ A,
                                                const ushort_t* __restrict__ B,
                                                float* __restrict__ C, int M, int N, int K,
                                                int nbx) {
  __shared__ __attribute__((aligned(16))) ushort_t As[64 * 64];
  __shared__ __attribute__((aligned(16))) ushort_t Bs[128 * 64];
  const int per = gridDim.x >> 3;
  const int fl = (blockIdx.x & 7) * per + (blockIdx.x >> 3);
  const int m0 = (fl / nbx) * 64, n0 = (fl % nbx) * 128;
  const int tid = threadIdx.x, w = tid >> 6, lane = tid & 63;
  const int wn = w * 32;
  const int l15 = lane & 15, l4 = lane >> 4;
  const int sw = ((lane & 7) ^ (lane >> 3)) << 3;
  f32x4 acc[4][2];
#pragma unroll
  for (int i = 0; i < 4; ++i)
#pragma unroll
    for (int j = 0; j < 2; ++j)
#pragma unroll
      for (int r = 0; r < 4; ++r) acc[i][j][r] = 0.f;

  for (int k0 = 0; k0 < K; k0 += 64) {
    __syncthreads();
#pragma unroll
    for (int r = 0; r < 2; ++r) {  // A rows w*16 + {0,8}
      int rowb = w * 16 + r * 8;
      const ushort_t* ga = A + (size_t)(m0 + rowb + (lane >> 3)) * K + k0 + sw;
      __builtin_amdgcn_global_load_lds((gvoid_t*)ga, (lvoid_t*)(As + rowb * 64), 16, 0, 0);
    }
#pragma unroll
    for (int r = 0; r < 4; ++r) {  // B rows w*32 + {0,8,16,24}
      int rowb = w * 32 + r * 8;
      const ushort_t* gb = B + (size_t)(n0 + rowb + (lane >> 3)) * K + k0 + sw;
      __builtin_amdgcn_global_load_lds((gvoid_t*)gb, (lvoid_t*)(Bs + rowb * 64), 16, 0, 0);
    }
    __syncthreads();
#pragma unroll
    for (int kk = 0; kk < 2; ++kk) {
      bf16x8 af[4], bfr[2];
#pragma unroll
      for (int i = 0; i < 4; ++i) {
        int row = i * 16 + l15;
        af[i] = *(const bf16x8*)&As[row * 64 + (((kk * 4 + l4) ^ (row & 7)) << 3)];
      }
#pragma unroll
      for (int j = 0; j < 2; ++j) {
        int row = wn + j * 16 + l15;
        bfr[j] = *(const bf16x8*)&Bs[row * 64 + (((kk * 4 + l4) ^ (row & 7)) << 3)];
      }
#pragma unroll
      for (int i = 0; i < 4; ++i)
#pragma unroll
        for (int j = 0; j < 2; ++j)
          acc[i][j] = __builtin_amdgcn_mfma_f32_16x16x32_bf16(af[i], bfr[j], acc[i][j], 0, 0, 0);
    }
  }
#pragma unroll
  for (int i = 0; i < 4; ++i)
#pragma unroll
    for (int j = 0; j < 2; ++j)
#pragma unroll
      for (int r = 0; r < 4; ++r)
        C[(size_t)(m0 + i * 16 + l4 * 4 + r) * N + n0 + wn + j * 16 + l15] = acc[i][j][r];
}

// ------------- V transpose: qkv V-part -> VT[bn][d][j] (bf16) -------------
__global__ __launch_bounds__(256) void k_vt(const ushort_t* __restrict__ qkv,
                                            ushort_t* __restrict__ vt) {
  __shared__ uint32 tile[64 * 65];
  const int jt = blockIdx.x, bn = blockIdx.y, b = bn & 1, n = bn >> 1;
  const int tid = threadIdx.x;
  const int j0 = jt * 64;
#pragma unroll
  for (int rr = 0; rr < 2; ++rr) {
    int lin = rr * 2048 + tid * 8;
    int j = lin >> 6, d0 = lin & 63;
    u16x8 v = *(const u16x8*)(qkv + (size_t)(j0 + j) * 6144 + b * 3072 + 2048 + n * 64 + d0);
#pragma unroll
    for (int e = 0; e < 8; ++e) tile[j * 65 + d0 + e] = v[e];
  }
  __syncthreads();
#pragma unroll
  for (int rr = 0; rr < 2; ++rr) {
    int lin = rr * 2048 + tid * 8;
    int d = lin >> 6, jj = lin & 63;
    u16x8 o;
#pragma unroll
    for (int e = 0; e < 8; ++e) o[e] = (ushort_t)tile[(jj + e) * 65 + d];
    *(u16x8*)(vt + ((size_t)bn * 64 + d) * 2048 + j0 + jj) = o;
  }
}

// ------------- flash attention, split-KV across blocks (z = KV half) -------------
// Fixed-max softmax: P = exp(s) (Q prescaled), l via per-lane VALU tree.
// Register-lean (jb-split). Loop-carried staging pointers; LDS[row][s]=src[row][s^g(row)],
// g(row) = (row&7)^((row>>3)&7).
__global__ __launch_bounds__(256, 4) void k_attn(const ushort_t* __restrict__ qkv,
                                                 const ushort_t* __restrict__ vt,
                                                 ushort_t* o0, ushort_t* o1,
                                                 float* __restrict__ l0,
                                                 float* __restrict__ l1) {
  __shared__ __attribute__((aligned(16))) ushort_t Ks[2][4096];
  __shared__ __attribute__((aligned(16))) ushort_t VTs[2][4096];
  const int bn = blockIdx.y, b = bn & 1, n = bn >> 1, z = blockIdx.z;
  const int tid = threadIdx.x, w = tid >> 6, lane = tid & 63;
  const int l31 = lane & 31, h = lane >> 5;
  const int qrow = blockIdx.x * 128 + w * 32 + l31;
  const size_t qoff = (size_t)qrow * 6144 + b * 3072 + n * 64;
  const float CEXP = 0.18033688011113723f;  // 0.125 * log2(e)
  bf16x8 qf[4];
#pragma unroll
  for (int ks = 0; ks < 4; ++ks) {
    u16x8 qv = *(const u16x8*)(qkv + qoff + ks * 16 + h * 8);
    union { u16x8 u; bf16x8 v; } cu;
#pragma unroll
    for (int e = 0; e < 8; ++e) cu.u[e] = f2bf(bf2f(qv[e]) * CEXP);
    qf[ks] = cu.v;
  }
  const int fA = (l31 & 7) ^ (l31 >> 3);
  const int fB = fA ^ 4;

  const int t0 = z * 16;  // this block's first KV tile
  const int sw0 = (((lane & 7) ^ (lane >> 3) ^ (w * 2)) & 7) << 3;
  const int sw1 = (((lane & 7) ^ (lane >> 3) ^ (w * 2 + 1)) & 7) << 3;
  const ushort_t* kp0 = qkv + (size_t)(t0 * 64 + w * 16 + (lane >> 3)) * 6144 + b * 3072 + n * 64 + 1024 + sw0;
  const ushort_t* kp1 = qkv + (size_t)(t0 * 64 + w * 16 + 8 + (lane >> 3)) * 6144 + b * 3072 + n * 64 + 1024 + sw1;
  const ushort_t* vp0 = vt + ((size_t)bn * 64 + w * 16 + (lane >> 3)) * 2048 + t0 * 64 + sw0;
  const ushort_t* vp1 = vt + ((size_t)bn * 64 + w * 16 + 8 + (lane >> 3)) * 2048 + t0 * 64 + sw1;
  const size_t KSTRIDE = (size_t)64 * 6144;

  // ---- prologue: stage tile t0 into buffer 0 ----
  __builtin_amdgcn_global_load_lds((gvoid_t*)kp0, (lvoid_t*)(Ks[0] + (w * 16) * 64), 16, 0, 0);
  __builtin_amdgcn_global_load_lds((gvoid_t*)kp1, (lvoid_t*)(Ks[0] + (w * 16 + 8) * 64), 16, 0, 0);
  __builtin_amdgcn_global_load_lds((gvoid_t*)vp0, (lvoid_t*)(VTs[0] + (w * 16) * 64), 16, 0, 0);
  __builtin_amdgcn_global_load_lds((gvoid_t*)vp1, (lvoid_t*)(VTs[0] + (w * 16 + 8) * 64), 16, 0, 0);
  kp0 += KSTRIDE; kp1 += KSTRIDE; vp0 += 64; vp1 += 64;
  __syncthreads();

  f32x16 oacc[2];
#pragma unroll
  for (int r = 0; r < 16; ++r) { oacc[0][r] = 0.f; oacc[1][r] = 0.f; }
  float lsum = 0.f;

  for (int t = 0; t < 16; ++t) {
    const ushort_t* Kb = Ks[t & 1];
    const ushort_t* Vb = VTs[t & 1];
    if (t < 15) {
      ushort_t* kw = Ks[(t + 1) & 1];
      ushort_t* vw = VTs[(t + 1) & 1];
      __builtin_amdgcn_global_load_lds((gvoid_t*)kp0, (lvoid_t*)(kw + (w * 16) * 64), 16, 0, 0);
      __builtin_amdgcn_global_load_lds((gvoid_t*)kp1, (lvoid_t*)(kw + (w * 16 + 8) * 64), 16, 0, 0);
      __builtin_amdgcn_global_load_lds((gvoid_t*)vp0, (lvoid_t*)(vw + (w * 16) * 64), 16, 0, 0);
      __builtin_amdgcn_global_load_lds((gvoid_t*)vp1, (lvoid_t*)(vw + (w * 16 + 8) * 64), 16, 0, 0);
      kp0 += KSTRIDE; kp1 += KSTRIDE; vp0 += 64; vp1 += 64;
    }
    // jb-split: QK(j-half) -> exp -> PV(2 slots) -> l-tree, sv reused per half
#pragma unroll
    for (int jb = 0; jb < 2; ++jb) {
      f32x16 sv;
#pragma unroll
      for (int r = 0; r < 16; ++r) sv[r] = 0.f;
      const int rb = (jb * 32 + l31) * 64;
      const int fj = jb ? fB : fA;
      __builtin_amdgcn_s_setprio(1);
#pragma unroll
      for (int ks = 0; ks < 4; ++ks) {
        bf16x8 kf = *(const bf16x8*)&Kb[rb + ((((ks << 1) | h) ^ fj) << 3)];
        sv = __builtin_amdgcn_mfma_f32_32x32x16_bf16(kf, qf[ks], sv, 0, 0, 0);
      }
      __builtin_amdgcn_s_setprio(0);
#pragma unroll
      for (int r = 0; r < 16; ++r) sv[r] = __builtin_amdgcn_exp2f(sv[r]);
      // PV slots for this j-half
#pragma unroll
      for (int ks2 = 0; ks2 < 2; ++ks2) {
        const int q0 = ks2 * 2;
        uint32 X0, X1, Y0, Y1;
        asm volatile("v_cvt_pk_bf16_f32 %0, %1, %2" : "=v"(X0) : "v"(sv[q0 * 4 + 0]), "v"(sv[q0 * 4 + 1]));
        asm volatile("v_cvt_pk_bf16_f32 %0, %1, %2" : "=v"(X1) : "v"(sv[q0 * 4 + 2]), "v"(sv[q0 * 4 + 3]));
        asm volatile("v_cvt_pk_bf16_f32 %0, %1, %2" : "=v"(Y0) : "v"(sv[(q0 + 1) * 4 + 0]), "v"(sv[(q0 + 1) * 4 + 1]));
        asm volatile("v_cvt_pk_bf16_f32 %0, %1, %2" : "=v"(Y1) : "v"(sv[(q0 + 1) * 4 + 2]), "v"(sv[(q0 + 1) * 4 + 3]));
        asm volatile("v_permlane32_swap_b32 %0, %1" : "+v"(X0), "+v"(Y0));
        asm volatile("v_permlane32_swap_b32 %0, %1" : "+v"(X1), "+v"(Y1));
        union { u32x4 u; bf16x8 v; } pf;
        pf.u[0] = X0; pf.u[1] = X1; pf.u[2] = Y0; pf.u[3] = Y1;
        const int c = ((jb * 2 + ks2) << 1) | h;
        bf16x8 vf0 = *(const bf16x8*)&Vb[l31 * 64 + ((c ^ fA) << 3)];
        bf16x8 vf1 = *(const bf16x8*)&Vb[(32 + l31) * 64 + ((c ^ fB) << 3)];
        __builtin_amdgcn_s_setprio(1);
        oacc[0] = __builtin_amdgcn_mfma_f32_32x32x16_bf16(vf0, pf.v, oacc[0], 0, 0, 0);
        oacc[1] = __builtin_amdgcn_mfma_f32_32x32x16_bf16(vf1, pf.v, oacc[1], 0, 0, 0);
        __builtin_amdgcn_s_setprio(0);
      }
      // l tree for this half (off critical path)
      float ls[8];
#pragma unroll
      for (int r = 0; r < 8; ++r) ls[r] = sv[r] + sv[r + 8];
#pragma unroll
      for (int st = 4; st >= 1; st >>= 1)
#pragma unroll
        for (int r = 0; r < st; ++r) ls[r] += ls[r + st];
      lsum += ls[0];
    }
    if (t < 15) __syncthreads();
  }
  const float l_run = lsum + __shfl_xor(lsum, 32);

  // ---- write RAW partials (bf16 O, fp32 l) ----
  ushort_t* op = (z == 0) ? (o0 + (size_t)qrow * 2048 + b * 1024 + n * 64)
                          : (o1 + (size_t)qrow * 6144 + b * 3072 + 2048 + n * 64);
#pragma unroll
  for (int db = 0; db < 2; ++db)
#pragma unroll
    for (int qq = 0; qq < 4; ++qq) {
      u16x4 st;
#pragma unroll
      for (int m = 0; m < 4; ++m) st[m] = f2bf(oacc[db][qq * 4 + m]);
      *(u16x4*)(op + db * 32 + qq * 8 + h * 4) = st;
    }
  if (h == 0) {
    float* lp = (z == 0) ? l0 : l1;
    lp[qrow * 32 + bn] = l_run;
  }
}

// ------------- combine halves + memory retrieval + gated injection -------------
__global__ __launch_bounds__(256) void k_gate2(const ushort_t* __restrict__ qkv,
                                               const ushort_t* __restrict__ o0,
                                               const float* __restrict__ l0,
                                               const float* __restrict__ l1,
                                               const float* __restrict__ mem,
                                               const float* __restrict__ mnorm,
                                               const float* __restrict__ gbeta,
                                               ushort_t* __restrict__ inj) {
  const int bn = blockIdx.y, b = bn & 1, n = bn >> 1;
  const int tid = threadIdx.x, w = tid >> 6, lane = tid & 63;
  const int l31 = lane & 31, h = lane >> 5;
  const int qrow = blockIdx.x * 128 + w * 32 + l31;
  const size_t qoff = (size_t)qrow * 6144 + b * 3072 + n * 64;

  float den = 0.f;
  bf16x8 cqf[4];
  const float* nrm = mnorm + (size_t)(b * NHEAD + n) * 64;
#pragma unroll
  for (int ks = 0; ks < 4; ++ks) {
    u16x8 qv = *(const u16x8*)(qkv + qoff + ks * 16 + h * 8);
    union { u16x8 u; bf16x8 v; } cu;
#pragma unroll
    for (int e = 0; e < 8; ++e) {
      float x = bf2f(qv[e]);
      float c = (x > 0.f) ? (x + 1.f) : __builtin_amdgcn_exp2f(x * 1.4426950408889634f);
      cu.u[e] = f2bf(c);
      den += c * nrm[ks * 16 + h * 8 + e];
    }
    cqf[ks] = cu.v;
  }
  den += __shfl_xor(den, 32);

  const float* mb = mem + (size_t)(b * NHEAD + n) * 4096;
  f32x16 accv[2];
#pragma unroll
  for (int r = 0; r < 16; ++r) { accv[0][r] = 0.f; accv[1][r] = 0.f; }
#pragma unroll
  for (int db = 0; db < 2; ++db)
#pragma unroll
    for (int ks = 0; ks < 4; ++ks) {
      union { u16x8 u; bf16x8 v; } af;
#pragma unroll
      for (int e = 0; e < 8; ++e)
        af.u[e] = f2bf(mb[(size_t)(ks * 16 + h * 8 + e) * 64 + db * 32 + l31]);
      accv[db] = __builtin_amdgcn_mfma_f32_32x32x16_bf16(af.v, cqf[ks], accv[db], 0, 0, 0);
    }

  const float lsum = l0[qrow * 32 + bn] + l1[qrow * 32 + bn];
  float g = 1.f / (1.f + expf(-gbeta[0]));
  float rden = 1.f / den, invl = 1.f / lsum;
  const ushort_t* p0 = o0 + (size_t)qrow * 2048 + b * 1024 + n * 64;
  const ushort_t* p1 = qkv + (size_t)qrow * 6144 + b * 3072 + 2048 + n * 64;
  ushort_t* op = inj + (size_t)qrow * 2048 + b * 1024 + n * 64;
#pragma unroll
  for (int db = 0; db < 2; ++db)
#pragma unroll
    for (int qq = 0; qq < 4; ++qq) {
      const int off = db * 32 + qq * 8 + h * 4;
      u16x4 a0 = *(const u16x4*)(p0 + off);
      u16x4 a1 = *(const u16x4*)(p1 + off);
      u16x4 st;
#pragma unroll
      for (int m = 0; m < 4; ++m) {
        float av = (bf2f(a0[m]) + bf2f(a1[m])) * invl;
        float content = accv[db][qq * 4 + m] * rden;
        st[m] = f2bf(g * content + (1.f - g) * av);
      }
      *(u16x4*)(op + off) = st;
    }
}

// ------------- y = h + attn_out; LayerNorm(D=1024) -------------
__global__ __launch_bounds__(256) void k_ln(const float* __restrict__ h,
                                            const float* __restrict__ ao,
                                            const float* __restrict__ gam,
                                            const float* __restrict__ bet,
                                            float* __restrict__ out) {
  const int m = blockIdx.x, t = threadIdx.x;
  const int lane = t & 63, w = t >> 6;
  __shared__ float redS[4], redQ[4];
  const size_t base = (size_t)m * 1024;
  float4 hv = ((const float4*)(h + base))[t];
  float4 avv = ((const float4*)(ao + base))[t];
  float y0 = hv.x + avv.x, y1 = hv.y + avv.y, y2 = hv.z + avv.z, y3 = hv.w + avv.w;
  float s = y0 + y1 + y2 + y3;
  float sq = y0 * y0 + y1 * y1 + y2 * y2 + y3 * y3;
#pragma unroll
  for (int mk = 32; mk >= 1; mk >>= 1) { s += __shfl_xor(s, mk); sq += __shfl_xor(sq, mk); }
  if (lane == 0) { redS[w] = s; redQ[w] = sq; }
  __syncthreads();
  float Ssum = redS[0] + redS[1] + redS[2] + redS[3];
  float Qsum = redQ[0] + redQ[1] + redQ[2] + redQ[3];
  float mu = Ssum * (1.f / 1024.f);
  float var = Qsum * (1.f / 1024.f) - mu * mu;
  float rstd = rsqrtf(var + 1e-5f);
  float4 g = ((const float4*)gam)[t];
  float4 bt = ((const float4*)bet)[t];
  float4 o;
  o.x = (y0 - mu) * rstd * g.x + bt.x;
  o.y = (y1 - mu) * rstd * g.y + bt.y;
  o.z = (y2 - mu) * rstd * g.z + bt.z;
  o.w = (y3 - mu) * rstd * g.w + bt.w;
  ((float4*)(out + base))[t] = o;
}

extern "C" void kernel_launch(void* const* d_in, const int* in_sizes, int n_in,
                              void* d_out, int out_size, void* d_ws, size_t ws_size,
                              hipStream_t stream) {
  const float* h = (const float*)d_in[0];
  const float* Wq = (const float*)d_in[1];
  const float* Wkv = (const float*)d_in[2];
  const float* Wo = (const float*)d_in[3];
  const float* gam = (const float*)d_in[4];
  const float* bet = (const float*)d_in[5];
  const float* mem = (const float*)d_in[6];
  const float* mnorm = (const float*)d_in[7];
  const float* gbeta = (const float*)d_in[8];
  float* out = (float*)d_out;

  char* ws = (char*)d_ws;
  // [0,8M)   hb  (gemm1 A)      -> O0 partials (attn z=0)
  // [8M,14M) wT  (gemm1 B)      -> l0 at [8M,+256K), l1 at [8M+256K,+256K)
  // [14M,16M) woT (gemm2 B)
  // [16M,40M) qkv (V-slots -> O1 partials during attn) -> ao fp32 after combine
  // [40M,48M) vt  (attn V^T)    -> inj (combine output, gemm2 A)
  ushort_t* hb  = (ushort_t*)(ws);
  ushort_t* wT  = (ushort_t*)(ws + (size_t)(8u << 20));
  ushort_t* woT = (ushort_t*)(ws + (size_t)(14u << 20));
  ushort_t* qkv = (ushort_t*)(ws + (size_t)(16u << 20));
  float*    ao  = (float*)   (ws + (size_t)(16u << 20));  // alias qkv (dead by then)
  ushort_t* vtb = (ushort_t*)(ws + (size_t)(40u << 20));
  ushort_t* o0  = hb;                                     // alias hb (dead by then)
  float*    l0  = (float*)(ws + (size_t)(8u << 20));      // alias wT (dead by then)
  float*    l1  = (float*)(ws + (size_t)(8u << 20) + (1u << 18));
  ushort_t* inj = vtb;                                    // alias vt (dead by then)

  k_cvt_all<<<dim3(64, 32, 4), 256, 0, stream>>>(h, Wq, Wkv, Wo, hb, wT, woT);
  k_gemm_bt<1><<<768, 256, 0, stream>>>(hb, wT, (void*)qkv, 4096, 3072, 1024, 24);
  k_vt<<<dim3(32, 32), 256, 0, stream>>>(qkv, vtb);
  k_attn<<<dim3(16, 32, 2), 256, 0, stream>>>(qkv, vtb, o0, qkv, l0, l1);
  k_gate2<<<dim3(16, 32), 256, 0, stream>>>(qkv, o0, l0, l1, mem, mnorm, gbeta, inj);
  k_gemm64<<<512, 256, 0, stream>>>(inj, woT, ao, 4096, 1024, 1024, 8);
  k_ln<<<4096, 256, 0, stream>>>(h, ao, gam, bet, out);
}

// Round 14
// 133.200 us; speedup vs baseline: 1.1291x; 1.0381x over previous
//
#include <hip/hip_runtime.h>

// InfiniAttn forward on gfx950.
// cvt (h + 3×W merged) | GEMM qkv (BK=64, swizzled LDS) | V-transpose | flash attn
// SPLIT-KV across blocks (fixed-max, register-lean, XCD-swizzled 1D grid) |
// combine+mem-gate | GEMM out (64x128, BK=64 swizzled, bf16 out) | +h,LN.

typedef unsigned short ushort_t;
typedef unsigned int uint32;

typedef __bf16 bf16x8 __attribute__((ext_vector_type(8)));
typedef float f32x4 __attribute__((ext_vector_type(4)));
typedef float f32x16 __attribute__((ext_vector_type(16)));
typedef unsigned short u16x8 __attribute__((ext_vector_type(8)));
typedef unsigned short u16x4 __attribute__((ext_vector_type(4)));
typedef unsigned int u32x4 __attribute__((ext_vector_type(4)));

typedef const __attribute__((address_space(1))) void gvoid_t;
typedef __attribute__((address_space(3))) void lvoid_t;

#define S_LEN 2048
#define BATCH 2
#define NHEAD 16

__device__ __forceinline__ ushort_t f2bf(float x) {
  union { float f; unsigned u; } c; c.f = x;
  unsigned r = (c.u + 0x7FFFu + ((c.u >> 16) & 1u)) >> 16;
  return (ushort_t)r;
}
__device__ __forceinline__ float bf2f(ushort_t v) {
  union { unsigned u; float f; } c; c.u = ((unsigned)v) << 16;
  return c.f;
}

// ------------- merged convert: z<3 -> W transpose-convert; z==3 -> h fp32->bf16 -------------
__global__ __launch_bounds__(256) void k_cvt_all(const float* __restrict__ h,
                                                 const float* __restrict__ Wq,
                                                 const float* __restrict__ Wkv,
                                                 const float* __restrict__ Wo,
                                                 ushort_t* __restrict__ hb,
                                                 ushort_t* __restrict__ wT,
                                                 ushort_t* __restrict__ woT) {
  const int z = blockIdx.z;
  if (z == 3) {  // h convert: 2048 blocks x 256 thr x 2 float4
    int idx = (blockIdx.y * 64 + blockIdx.x) * 256 + threadIdx.x;
#pragma unroll
    for (int i = 0; i < 2; ++i) {
      int e = idx + i * 524288;
      float4 v = ((const float4*)h)[e];
      u16x4 o; o[0] = f2bf(v.x); o[1] = f2bf(v.y); o[2] = f2bf(v.z); o[3] = f2bf(v.w);
      ((u16x4*)hb)[e] = o;
    }
    return;
  }
  const float* W;
  ushort_t* WT;
  int N;
  if (z == 0)      { W = Wq;  WT = wT;                        N = 1024; }
  else if (z == 1) { W = Wkv; WT = wT + (size_t)1024 * 1024;  N = 2048; }
  else             { W = Wo;  WT = woT;                       N = 1024; }
  const int K = 1024;
  if (blockIdx.x * 32 >= N) return;
  __shared__ float tile[32][33];
  const int n0 = blockIdx.x * 32, k0 = blockIdx.y * 32;
  const int tx = threadIdx.x & 31, ty = threadIdx.x >> 5;
#pragma unroll
  for (int r = 0; r < 32; r += 8)
    tile[ty + r][tx] = W[(size_t)(k0 + ty + r) * N + n0 + tx];
  __syncthreads();
#pragma unroll
  for (int r = 0; r < 32; r += 8)
    WT[(size_t)(n0 + ty + r) * K + k0 + tx] = f2bf(tile[tx][ty + r]);
}

// ------------- GEMM 128x128, BK=64: C = A[M][K](bf16) * B[N][K]^T(bf16) -------------
// LDS [128 rows][8 slots x 8 shorts]; LDS[row][s] = src[row][s ^ (row&7)].
template <int OUT_BF16>
__global__ __launch_bounds__(256) void k_gemm_bt(const ushort_t* __restrict__ A,
                                                 const ushort_t* __restrict__ B,
                                                 void* __restrict__ Cv, int M, int N, int K,
                                                 int nbx) {
  __shared__ __attribute__((aligned(16))) ushort_t As[128 * 64];
  __shared__ __attribute__((aligned(16))) ushort_t Bs[128 * 64];
  const int per = gridDim.x >> 3;  // grid % 8 == 0
  const int fl = (blockIdx.x & 7) * per + (blockIdx.x >> 3);
  const int m0 = (fl / nbx) * 128, n0 = (fl % nbx) * 128;
  const int tid = threadIdx.x, w = tid >> 6, lane = tid & 63;
  const int wm = (w >> 1) * 64, wn = (w & 1) * 64;
  const int l15 = lane & 15, l4 = lane >> 4;
  const int sw = ((lane & 7) ^ (lane >> 3)) << 3;  // source col pre-swizzle (shorts)
  f32x4 acc[4][4];
#pragma unroll
  for (int i = 0; i < 4; ++i)
#pragma unroll
    for (int j = 0; j < 4; ++j)
#pragma unroll
      for (int r = 0; r < 4; ++r) acc[i][j][r] = 0.f;

  for (int k0 = 0; k0 < K; k0 += 64) {
    __syncthreads();
#pragma unroll
    for (int r = 0; r < 4; ++r) {
      int rowb = r * 32 + w * 8;  // rows rowb..rowb+7; rowb % 8 == 0
      const ushort_t* ga = A + (size_t)(m0 + rowb + (lane >> 3)) * K + k0 + sw;
      const ushort_t* gb = B + (size_t)(n0 + rowb + (lane >> 3)) * K + k0 + sw;
      __builtin_amdgcn_global_load_lds((gvoid_t*)ga, (lvoid_t*)(As + rowb * 64), 16, 0, 0);
      __builtin_amdgcn_global_load_lds((gvoid_t*)gb, (lvoid_t*)(Bs + rowb * 64), 16, 0, 0);
    }
    __syncthreads();
#pragma unroll
    for (int kk = 0; kk < 2; ++kk) {
      bf16x8 af[4], bfr[4];
#pragma unroll
      for (int i = 0; i < 4; ++i) {
        int row = wm + i * 16 + l15;
        af[i] = *(const bf16x8*)&As[row * 64 + (((kk * 4 + l4) ^ (row & 7)) << 3)];
      }
#pragma unroll
      for (int j = 0; j < 4; ++j) {
        int row = wn + j * 16 + l15;
        bfr[j] = *(const bf16x8*)&Bs[row * 64 + (((kk * 4 + l4) ^ (row & 7)) << 3)];
      }
#pragma unroll
      for (int i = 0; i < 4; ++i)
#pragma unroll
        for (int j = 0; j < 4; ++j)
          acc[i][j] = __builtin_amdgcn_mfma_f32_16x16x32_bf16(af[i], bfr[j], acc[i][j], 0, 0, 0);
    }
  }
#pragma unroll
  for (int i = 0; i < 4; ++i)
#pragma unroll
    for (int j = 0; j < 4; ++j)
#pragma unroll
      for (int r = 0; r < 4; ++r) {
        int row = m0 + wm + i * 16 + l4 * 4 + r;
        int col = n0 + wn + j * 16 + l15;
        if (OUT_BF16)
          ((ushort_t*)Cv)[(size_t)row * N + col] = f2bf(acc[i][j][r]);
        else
          ((float*)Cv)[(size_t)row * N + col] = acc[i][j][r];
      }
}

// ------------- GEMM 64x128 tiles, BK=64 swizzled, bf16 out (512 blocks) -------------
__global__ __launch_bounds__(256) void k_gemm64(const ushort_t* __restrict__ A,
                                                const ushort_t* __restrict__ B,
                                                ushort_t* __restrict__ C, int M, int N, int K,
                                                int nbx) {
  __shared__ __attribute__((aligned(16))) ushort_t As[64 * 64];
  __shared__ __attribute__((aligned(16))) ushort_t Bs[128 * 64];
  const int per = gridDim.x >> 3;
  const int fl = (blockIdx.x & 7) * per + (blockIdx.x >> 3);
  const int m0 = (fl / nbx) * 64, n0 = (fl % nbx) * 128;
  const int tid = threadIdx.x, w = tid >> 6, lane = tid & 63;
  const int wn = w * 32;
  const int l15 = lane & 15, l4 = lane >> 4;
  const int sw = ((lane & 7) ^ (lane >> 3)) << 3;
  f32x4 acc[4][2];
#pragma unroll
  for (int i = 0; i < 4; ++i)
#pragma unroll
    for (int j = 0; j < 2; ++j)
#pragma unroll
      for (int r = 0; r < 4; ++r) acc[i][j][r] = 0.f;

  for (int k0 = 0; k0 < K; k0 += 64) {
    __syncthreads();
#pragma unroll
    for (int r = 0; r < 2; ++r) {  // A rows w*16 + {0,8}
      int rowb = w * 16 + r * 8;
      const ushort_t* ga = A + (size_t)(m0 + rowb + (lane >> 3)) * K + k0 + sw;
      __builtin_amdgcn_global_load_lds((gvoid_t*)ga, (lvoid_t*)(As + rowb * 64), 16, 0, 0);
    }
#pragma unroll
    for (int r = 0; r < 4; ++r) {  // B rows w*32 + {0,8,16,24}
      int rowb = w * 32 + r * 8;
      const ushort_t* gb = B + (size_t)(n0 + rowb + (lane >> 3)) * K + k0 + sw;
      __builtin_amdgcn_global_load_lds((gvoid_t*)gb, (lvoid_t*)(Bs + rowb * 64), 16, 0, 0);
    }
    __syncthreads();
#pragma unroll
    for (int kk = 0; kk < 2; ++kk) {
      bf16x8 af[4], bfr[2];
#pragma unroll
      for (int i = 0; i < 4; ++i) {
        int row = i * 16 + l15;
        af[i] = *(const bf16x8*)&As[row * 64 + (((kk * 4 + l4) ^ (row & 7)) << 3)];
      }
#pragma unroll
      for (int j = 0; j < 2; ++j) {
        int row = wn + j * 16 + l15;
        bfr[j] = *(const bf16x8*)&Bs[row * 64 + (((kk * 4 + l4) ^ (row & 7)) << 3)];
      }
#pragma unroll
      for (int i = 0; i < 4; ++i)
#pragma unroll
        for (int j = 0; j < 2; ++j)
          acc[i][j] = __builtin_amdgcn_mfma_f32_16x16x32_bf16(af[i], bfr[j], acc[i][j], 0, 0, 0);
    }
  }
#pragma unroll
  for (int i = 0; i < 4; ++i)
#pragma unroll
    for (int j = 0; j < 2; ++j)
#pragma unroll
      for (int r = 0; r < 4; ++r)
        C[(size_t)(m0 + i * 16 + l4 * 4 + r) * N + n0 + wn + j * 16 + l15] = f2bf(acc[i][j][r]);
}

// ------------- V transpose: qkv V-part -> VT[bn][d][j] (bf16) -------------
__global__ __launch_bounds__(256) void k_vt(const ushort_t* __restrict__ qkv,
                                            ushort_t* __restrict__ vt) {
  __shared__ uint32 tile[64 * 65];
  const int jt = blockIdx.x, bn = blockIdx.y, b = bn & 1, n = bn >> 1;
  const int tid = threadIdx.x;
  const int j0 = jt * 64;
#pragma unroll
  for (int rr = 0; rr < 2; ++rr) {
    int lin = rr * 2048 + tid * 8;
    int j = lin >> 6, d0 = lin & 63;
    u16x8 v = *(const u16x8*)(qkv + (size_t)(j0 + j) * 6144 + b * 3072 + 2048 + n * 64 + d0);
#pragma unroll
    for (int e = 0; e < 8; ++e) tile[j * 65 + d0 + e] = v[e];
  }
  __syncthreads();
#pragma unroll
  for (int rr = 0; rr < 2; ++rr) {
    int lin = rr * 2048 + tid * 8;
    int d = lin >> 6, jj = lin & 63;
    u16x8 o;
#pragma unroll
    for (int e = 0; e < 8; ++e) o[e] = (ushort_t)tile[(jj + e) * 65 + d];
    *(u16x8*)(vt + ((size_t)bn * 64 + d) * 2048 + j0 + jj) = o;
  }
}

// ------------- flash attention, split-KV across blocks, XCD-swizzled 1D grid -------------
// fl = (bid&7)*128 + bid>>3: each XCD's L2 serves 8 (bn,z) groups x 16 qblocks,
// so K/V (2 MB/XCD) are fetched from HBM once per XCD instead of 8x.
// Fixed-max softmax: P = exp(s) (Q prescaled), l via per-lane VALU tree.
// Register-lean (jb-split). LDS[row][s]=src[row][s^g(row)], g(row)=(row&7)^((row>>3)&7).
__global__ __launch_bounds__(256, 4) void k_attn(const ushort_t* __restrict__ qkv,
                                                 const ushort_t* __restrict__ vt,
                                                 ushort_t* o0, ushort_t* o1,
                                                 float* __restrict__ l0,
                                                 float* __restrict__ l1) {
  __shared__ __attribute__((aligned(16))) ushort_t Ks[2][4096];
  __shared__ __attribute__((aligned(16))) ushort_t VTs[2][4096];
  const int bid = blockIdx.x;
  const int fl = (bid & 7) * 128 + (bid >> 3);  // bijective, 1024 % 8 == 0
  const int qb = fl & 15, bn = (fl >> 4) & 31, z = fl >> 9;
  const int b = bn & 1, n = bn >> 1;
  const int tid = threadIdx.x, w = tid >> 6, lane = tid & 63;
  const int l31 = lane & 31, h = lane >> 5;
  const int qrow = qb * 128 + w * 32 + l31;
  const size_t qoff = (size_t)qrow * 6144 + b * 3072 + n * 64;
  const float CEXP = 0.18033688011113723f;  // 0.125 * log2(e)
  bf16x8 qf[4];
#pragma unroll
  for (int ks = 0; ks < 4; ++ks) {
    u16x8 qv = *(const u16x8*)(qkv + qoff + ks * 16 + h * 8);
    union { u16x8 u; bf16x8 v; } cu;
#pragma unroll
    for (int e = 0; e < 8; ++e) cu.u[e] = f2bf(bf2f(qv[e]) * CEXP);
    qf[ks] = cu.v;
  }
  const int fA = (l31 & 7) ^ (l31 >> 3);
  const int fB = fA ^ 4;

  const int t0 = z * 16;  // this block's first KV tile
  const int sw0 = (((lane & 7) ^ (lane >> 3) ^ (w * 2)) & 7) << 3;
  const int sw1 = (((lane & 7) ^ (lane >> 3) ^ (w * 2 + 1)) & 7) << 3;
  const ushort_t* kp0 = qkv + (size_t)(t0 * 64 + w * 16 + (lane >> 3)) * 6144 + b * 3072 + n * 64 + 1024 + sw0;
  const ushort_t* kp1 = qkv + (size_t)(t0 * 64 + w * 16 + 8 + (lane >> 3)) * 6144 + b * 3072 + n * 64 + 1024 + sw1;
  const ushort_t* vp0 = vt + ((size_t)bn * 64 + w * 16 + (lane >> 3)) * 2048 + t0 * 64 + sw0;
  const ushort_t* vp1 = vt + ((size_t)bn * 64 + w * 16 + 8 + (lane >> 3)) * 2048 + t0 * 64 + sw1;
  const size_t KSTRIDE = (size_t)64 * 6144;

  // ---- prologue: stage tile t0 into buffer 0 ----
  __builtin_amdgcn_global_load_lds((gvoid_t*)kp0, (lvoid_t*)(Ks[0] + (w * 16) * 64), 16, 0, 0);
  __builtin_amdgcn_global_load_lds((gvoid_t*)kp1, (lvoid_t*)(Ks[0] + (w * 16 + 8) * 64), 16, 0, 0);
  __builtin_amdgcn_global_load_lds((gvoid_t*)vp0, (lvoid_t*)(VTs[0] + (w * 16) * 64), 16, 0, 0);
  __builtin_amdgcn_global_load_lds((gvoid_t*)vp1, (lvoid_t*)(VTs[0] + (w * 16 + 8) * 64), 16, 0, 0);
  kp0 += KSTRIDE; kp1 += KSTRIDE; vp0 += 64; vp1 += 64;
  __syncthreads();

  f32x16 oacc[2];
#pragma unroll
  for (int r = 0; r < 16; ++r) { oacc[0][r] = 0.f; oacc[1][r] = 0.f; }
  float lsum = 0.f;

  for (int t = 0; t < 16; ++t) {
    const ushort_t* Kb = Ks[t & 1];
    const ushort_t* Vb = VTs[t & 1];
    if (t < 15) {
      ushort_t* kw = Ks[(t + 1) & 1];
      ushort_t* vw = VTs[(t + 1) & 1];
      __builtin_amdgcn_global_load_lds((gvoid_t*)kp0, (lvoid_t*)(kw + (w * 16) * 64), 16, 0, 0);
      __builtin_amdgcn_global_load_lds((gvoid_t*)kp1, (lvoid_t*)(kw + (w * 16 + 8) * 64), 16, 0, 0);
      __builtin_amdgcn_global_load_lds((gvoid_t*)vp0, (lvoid_t*)(vw + (w * 16) * 64), 16, 0, 0);
      __builtin_amdgcn_global_load_lds((gvoid_t*)vp1, (lvoid_t*)(vw + (w * 16 + 8) * 64), 16, 0, 0);
      kp0 += KSTRIDE; kp1 += KSTRIDE; vp0 += 64; vp1 += 64;
    }
    // jb-split: QK(j-half) -> exp -> PV(2 slots) -> l-tree, sv reused per half
#pragma unroll
    for (int jb = 0; jb < 2; ++jb) {
      f32x16 sv;
#pragma unroll
      for (int r = 0; r < 16; ++r) sv[r] = 0.f;
      const int rb = (jb * 32 + l31) * 64;
      const int fj = jb ? fB : fA;
      __builtin_amdgcn_s_setprio(1);
#pragma unroll
      for (int ks = 0; ks < 4; ++ks) {
        bf16x8 kf = *(const bf16x8*)&Kb[rb + ((((ks << 1) | h) ^ fj) << 3)];
        sv = __builtin_amdgcn_mfma_f32_32x32x16_bf16(kf, qf[ks], sv, 0, 0, 0);
      }
      __builtin_amdgcn_s_setprio(0);
#pragma unroll
      for (int r = 0; r < 16; ++r) sv[r] = __builtin_amdgcn_exp2f(sv[r]);
      // PV slots for this j-half
#pragma unroll
      for (int ks2 = 0; ks2 < 2; ++ks2) {
        const int q0 = ks2 * 2;
        uint32 X0, X1, Y0, Y1;
        asm volatile("v_cvt_pk_bf16_f32 %0, %1, %2" : "=v"(X0) : "v"(sv[q0 * 4 + 0]), "v"(sv[q0 * 4 + 1]));
        asm volatile("v_cvt_pk_bf16_f32 %0, %1, %2" : "=v"(X1) : "v"(sv[q0 * 4 + 2]), "v"(sv[q0 * 4 + 3]));
        asm volatile("v_cvt_pk_bf16_f32 %0, %1, %2" : "=v"(Y0) : "v"(sv[(q0 + 1) * 4 + 0]), "v"(sv[(q0 + 1) * 4 + 1]));
        asm volatile("v_cvt_pk_bf16_f32 %0, %1, %2" : "=v"(Y1) : "v"(sv[(q0 + 1) * 4 + 2]), "v"(sv[(q0 + 1) * 4 + 3]));
        asm volatile("v_permlane32_swap_b32 %0, %1" : "+v"(X0), "+v"(Y0));
        asm volatile("v_permlane32_swap_b32 %0, %1" : "+v"(X1), "+v"(Y1));
        union { u32x4 u; bf16x8 v; } pf;
        pf.u[0] = X0; pf.u[1] = X1; pf.u[2] = Y0; pf.u[3] = Y1;
        const int c = ((jb * 2 + ks2) << 1) | h;
        bf16x8 vf0 = *(const bf16x8*)&Vb[l31 * 64 + ((c ^ fA) << 3)];
        bf16x8 vf1 = *(const bf16x8*)&Vb[(32 + l31) * 64 + ((c ^ fB) << 3)];
        __builtin_amdgcn_s_setprio(1);
        oacc[0] = __builtin_amdgcn_mfma_f32_32x32x16_bf16(vf0, pf.v, oacc[0], 0, 0, 0);
        oacc[1] = __builtin_amdgcn_mfma_f32_32x32x16_bf16(vf1, pf.v, oacc[1], 0, 0, 0);
        __builtin_amdgcn_s_setprio(0);
      }
      // l tree for this half (off critical path)
      float ls[8];
#pragma unroll
      for (int r = 0; r < 8; ++r) ls[r] = sv[r] + sv[r + 8];
#pragma unroll
      for (int st = 4; st >= 1; st >>= 1)
#pragma unroll
        for (int r = 0; r < st; ++r) ls[r] += ls[r + st];
      lsum += ls[0];
    }
    if (t < 15) __syncthreads();
  }
  const float l_run = lsum + __shfl_xor(lsum, 32);

  // ---- write RAW partials (bf16 O, fp32 l) ----
  ushort_t* op = (z == 0) ? (o0 + (size_t)qrow * 2048 + b * 1024 + n * 64)
                          : (o1 + (size_t)qrow * 6144 + b * 3072 + 2048 + n * 64);
#pragma unroll
  for (int db = 0; db < 2; ++db)
#pragma unroll
    for (int qq = 0; qq < 4; ++qq) {
      u16x4 st;
#pragma unroll
      for (int m = 0; m < 4; ++m) st[m] = f2bf(oacc[db][qq * 4 + m]);
      *(u16x4*)(op + db * 32 + qq * 8 + h * 4) = st;
    }
  if (h == 0) {
    float* lp = (z == 0) ? l0 : l1;
    lp[qrow * 32 + bn] = l_run;
  }
}

// ------------- combine halves + memory retrieval + gated injection -------------
__global__ __launch_bounds__(256) void k_gate2(const ushort_t* __restrict__ qkv,
                                               const ushort_t* __restrict__ o0,
                                               const float* __restrict__ l0,
                                               const float* __restrict__ l1,
                                               const float* __restrict__ mem,
                                               const float* __restrict__ mnorm,
                                               const float* __restrict__ gbeta,
                                               ushort_t* __restrict__ inj) {
  const int bn = blockIdx.y, b = bn & 1, n = bn >> 1;
  const int tid = threadIdx.x, w = tid >> 6, lane = tid & 63;
  const int l31 = lane & 31, h = lane >> 5;
  const int qrow = blockIdx.x * 128 + w * 32 + l31;
  const size_t qoff = (size_t)qrow * 6144 + b * 3072 + n * 64;

  float den = 0.f;
  bf16x8 cqf[4];
  const float* nrm = mnorm + (size_t)(b * NHEAD + n) * 64;
#pragma unroll
  for (int ks = 0; ks < 4; ++ks) {
    u16x8 qv = *(const u16x8*)(qkv + qoff + ks * 16 + h * 8);
    union { u16x8 u; bf16x8 v; } cu;
#pragma unroll
    for (int e = 0; e < 8; ++e) {
      float x = bf2f(qv[e]);
      float c = (x > 0.f) ? (x + 1.f) : __builtin_amdgcn_exp2f(x * 1.4426950408889634f);
      cu.u[e] = f2bf(c);
      den += c * nrm[ks * 16 + h * 8 + e];
    }
    cqf[ks] = cu.v;
  }
  den += __shfl_xor(den, 32);

  const float* mb = mem + (size_t)(b * NHEAD + n) * 4096;
  f32x16 accv[2];
#pragma unroll
  for (int r = 0; r < 16; ++r) { accv[0][r] = 0.f; accv[1][r] = 0.f; }
#pragma unroll
  for (int db = 0; db < 2; ++db)
#pragma unroll
    for (int ks = 0; ks < 4; ++ks) {
      union { u16x8 u; bf16x8 v; } af;
#pragma unroll
      for (int e = 0; e < 8; ++e)
        af.u[e] = f2bf(mb[(size_t)(ks * 16 + h * 8 + e) * 64 + db * 32 + l31]);
      accv[db] = __builtin_amdgcn_mfma_f32_32x32x16_bf16(af.v, cqf[ks], accv[db], 0, 0, 0);
    }

  const float lsum = l0[qrow * 32 + bn] + l1[qrow * 32 + bn];
  float g = 1.f / (1.f + expf(-gbeta[0]));
  float rden = 1.f / den, invl = 1.f / lsum;
  const ushort_t* p0 = o0 + (size_t)qrow * 2048 + b * 1024 + n * 64;
  const ushort_t* p1 = qkv + (size_t)qrow * 6144 + b * 3072 + 2048 + n * 64;
  ushort_t* op = inj + (size_t)qrow * 2048 + b * 1024 + n * 64;
#pragma unroll
  for (int db = 0; db < 2; ++db)
#pragma unroll
    for (int qq = 0; qq < 4; ++qq) {
      const int off = db * 32 + qq * 8 + h * 4;
      u16x4 a0 = *(const u16x4*)(p0 + off);
      u16x4 a1 = *(const u16x4*)(p1 + off);
      u16x4 st;
#pragma unroll
      for (int m = 0; m < 4; ++m) {
        float av = (bf2f(a0[m]) + bf2f(a1[m])) * invl;
        float content = accv[db][qq * 4 + m] * rden;
        st[m] = f2bf(g * content + (1.f - g) * av);
      }
      *(u16x4*)(op + off) = st;
    }
}

// ------------- y = h + attn_out(bf16); LayerNorm(D=1024) -------------
__global__ __launch_bounds__(256) void k_ln(const float* __restrict__ h,
                                            const ushort_t* __restrict__ aob,
                                            const float* __restrict__ gam,
                                            const float* __restrict__ bet,
                                            float* __restrict__ out) {
  const int m = blockIdx.x, t = threadIdx.x;
  const int lane = t & 63, w = t >> 6;
  __shared__ float redS[4], redQ[4];
  const size_t base = (size_t)m * 1024;
  float4 hv = ((const float4*)(h + base))[t];
  u16x4 av4 = ((const u16x4*)(aob + base))[t];
  float y0 = hv.x + bf2f(av4[0]), y1 = hv.y + bf2f(av4[1]);
  float y2 = hv.z + bf2f(av4[2]), y3 = hv.w + bf2f(av4[3]);
  float s = y0 + y1 + y2 + y3;
  float sq = y0 * y0 + y1 * y1 + y2 * y2 + y3 * y3;
#pragma unroll
  for (int mk = 32; mk >= 1; mk >>= 1) { s += __shfl_xor(s, mk); sq += __shfl_xor(sq, mk); }
  if (lane == 0) { redS[w] = s; redQ[w] = sq; }
  __syncthreads();
  float Ssum = redS[0] + redS[1] + redS[2] + redS[3];
  float Qsum = redQ[0] + redQ[1] + redQ[2] + redQ[3];
  float mu = Ssum * (1.f / 1024.f);
  float var = Qsum * (1.f / 1024.f) - mu * mu;
  float rstd = rsqrtf(var + 1e-5f);
  float4 g = ((const float4*)gam)[t];
  float4 bt = ((const float4*)bet)[t];
  float4 o;
  o.x = (y0 - mu) * rstd * g.x + bt.x;
  o.y = (y1 - mu) * rstd * g.y + bt.y;
  o.z = (y2 - mu) * rstd * g.z + bt.z;
  o.w = (y3 - mu) * rstd * g.w + bt.w;
  ((float4*)(out + base))[t] = o;
}

extern "C" void kernel_launch(void* const* d_in, const int* in_sizes, int n_in,
                              void* d_out, int out_size, void* d_ws, size_t ws_size,
                              hipStream_t stream) {
  const float* h = (const float*)d_in[0];
  const float* Wq = (const float*)d_in[1];
  const float* Wkv = (const float*)d_in[2];
  const float* Wo = (const float*)d_in[3];
  const float* gam = (const float*)d_in[4];
  const float* bet = (const float*)d_in[5];
  const float* mem = (const float*)d_in[6];
  const float* mnorm = (const float*)d_in[7];
  const float* gbeta = (const float*)d_in[8];
  float* out = (float*)d_out;

  char* ws = (char*)d_ws;
  // [0,8M)   hb  (gemm1 A)      -> O0 partials (attn z=0)
  // [8M,14M) wT  (gemm1 B)      -> l0 at [8M,+256K), l1 at [8M+256K,+256K)
  // [14M,16M) woT (gemm2 B)
  // [16M,40M) qkv (V-slots -> O1 partials during attn) -> aob bf16 after gate2
  // [40M,48M) vt  (attn V^T)    -> inj (combine output, gemm2 A)
  ushort_t* hb  = (ushort_t*)(ws);
  ushort_t* wT  = (ushort_t*)(ws + (size_t)(8u << 20));
  ushort_t* woT = (ushort_t*)(ws + (size_t)(14u << 20));
  ushort_t* qkv = (ushort_t*)(ws + (size_t)(16u << 20));
  ushort_t* aob = (ushort_t*)(ws + (size_t)(16u << 20));  // alias qkv (dead by then)
  ushort_t* vtb = (ushort_t*)(ws + (size_t)(40u << 20));
  ushort_t* o0  = hb;                                     // alias hb (dead by then)
  float*    l0  = (float*)(ws + (size_t)(8u << 20));      // alias wT (dead by then)
  float*    l1  = (float*)(ws + (size_t)(8u << 20) + (1u << 18));
  ushort_t* inj = vtb;                                    // alias vt (dead by then)

  k_cvt_all<<<dim3(64, 32, 4), 256, 0, stream>>>(h, Wq, Wkv, Wo, hb, wT, woT);
  k_gemm_bt<1><<<768, 256, 0, stream>>>(hb, wT, (void*)qkv, 4096, 3072, 1024, 24);
  k_vt<<<dim3(32, 32), 256, 0, stream>>>(qkv, vtb);
  k_attn<<<1024, 256, 0, stream>>>(qkv, vtb, o0, qkv, l0, l1);
  k_gate2<<<dim3(16, 32), 256, 0, stream>>>(qkv, o0, l0, l1, mem, mnorm, gbeta, inj);
  k_gemm64<<<512, 256, 0, stream>>>(inj, woT, aob, 4096, 1024, 1024, 8);
  k_ln<<<4096, 256, 0, stream>>>(h, aob, gam, bet, out);
}

// Round 15
// 130.487 us; speedup vs baseline: 1.1526x; 1.0208x over previous
//
#include <hip/hip_runtime.h>

// InfiniAttn forward on gfx950.
// cvt (h + 3×W merged) | GEMM qkv (BK=64, swizzled LDS; V-blocks write vt transposed
// via LDS epilogue — k_vt eliminated) | flash attn SPLIT-KV across blocks (fixed-max,
// register-lean, XCD-swizzled) | combine+mem-gate | GEMM out (bf16) | +h,LN.

typedef unsigned short ushort_t;
typedef unsigned int uint32;

typedef __bf16 bf16x8 __attribute__((ext_vector_type(8)));
typedef float f32x4 __attribute__((ext_vector_type(4)));
typedef float f32x16 __attribute__((ext_vector_type(16)));
typedef unsigned short u16x8 __attribute__((ext_vector_type(8)));
typedef unsigned short u16x4 __attribute__((ext_vector_type(4)));
typedef unsigned int u32x4 __attribute__((ext_vector_type(4)));

typedef const __attribute__((address_space(1))) void gvoid_t;
typedef __attribute__((address_space(3))) void lvoid_t;

#define S_LEN 2048
#define BATCH 2
#define NHEAD 16

__device__ __forceinline__ ushort_t f2bf(float x) {
  union { float f; unsigned u; } c; c.f = x;
  unsigned r = (c.u + 0x7FFFu + ((c.u >> 16) & 1u)) >> 16;
  return (ushort_t)r;
}
__device__ __forceinline__ float bf2f(ushort_t v) {
  union { unsigned u; float f; } c; c.u = ((unsigned)v) << 16;
  return c.f;
}

// ------------- merged convert: z<3 -> W transpose-convert; z==3 -> h fp32->bf16 -------------
__global__ __launch_bounds__(256) void k_cvt_all(const float* __restrict__ h,
                                                 const float* __restrict__ Wq,
                                                 const float* __restrict__ Wkv,
                                                 const float* __restrict__ Wo,
                                                 ushort_t* __restrict__ hb,
                                                 ushort_t* __restrict__ wT,
                                                 ushort_t* __restrict__ woT) {
  const int z = blockIdx.z;
  if (z == 3) {  // h convert: 2048 blocks x 256 thr x 2 float4
    int idx = (blockIdx.y * 64 + blockIdx.x) * 256 + threadIdx.x;
#pragma unroll
    for (int i = 0; i < 2; ++i) {
      int e = idx + i * 524288;
      float4 v = ((const float4*)h)[e];
      u16x4 o; o[0] = f2bf(v.x); o[1] = f2bf(v.y); o[2] = f2bf(v.z); o[3] = f2bf(v.w);
      ((u16x4*)hb)[e] = o;
    }
    return;
  }
  const float* W;
  ushort_t* WT;
  int N;
  if (z == 0)      { W = Wq;  WT = wT;                        N = 1024; }
  else if (z == 1) { W = Wkv; WT = wT + (size_t)1024 * 1024;  N = 2048; }
  else             { W = Wo;  WT = woT;                       N = 1024; }
  const int K = 1024;
  if (blockIdx.x * 32 >= N) return;
  __shared__ float tile[32][33];
  const int n0 = blockIdx.x * 32, k0 = blockIdx.y * 32;
  const int tx = threadIdx.x & 31, ty = threadIdx.x >> 5;
#pragma unroll
  for (int r = 0; r < 32; r += 8)
    tile[ty + r][tx] = W[(size_t)(k0 + ty + r) * N + n0 + tx];
  __syncthreads();
#pragma unroll
  for (int r = 0; r < 32; r += 8)
    WT[(size_t)(n0 + ty + r) * K + k0 + tx] = f2bf(tile[tx][ty + r]);
}

// ------------- GEMM 128x128, BK=64: qkv = hb * wT^T; V-blocks write vt transposed -------------
// Main loop LDS [128 rows][8 slots x 8 shorts]; LDS[row][s] = src[row][s ^ (row&7)].
// V-block epilogue: stage C tile [tok][col] (XOR-swizzled) in the same 32KB, then
// write vt[(n*2+b)*64+d][s] coalesced. Row-major V is never written to qkv (its slots
// are later filled by attn's O1 partials).
__global__ __launch_bounds__(256) void k_gemm_bt(const ushort_t* __restrict__ A,
                                                 const ushort_t* __restrict__ B,
                                                 ushort_t* __restrict__ C,
                                                 ushort_t* __restrict__ vt,
                                                 int M, int N, int K, int nbx) {
  __shared__ __attribute__((aligned(16))) ushort_t smem[16384];
  ushort_t* As = smem;
  ushort_t* Bs = smem + 8192;
  const int per = gridDim.x >> 3;  // grid % 8 == 0
  const int fl = (blockIdx.x & 7) * per + (blockIdx.x >> 3);
  const int m0 = (fl / nbx) * 128, n0 = (fl % nbx) * 128;
  const int tid = threadIdx.x, w = tid >> 6, lane = tid & 63;
  const int wm = (w >> 1) * 64, wn = (w & 1) * 64;
  const int l15 = lane & 15, l4 = lane >> 4;
  const int sw = ((lane & 7) ^ (lane >> 3)) << 3;  // source col pre-swizzle (shorts)
  f32x4 acc[4][4];
#pragma unroll
  for (int i = 0; i < 4; ++i)
#pragma unroll
    for (int j = 0; j < 4; ++j)
#pragma unroll
      for (int r = 0; r < 4; ++r) acc[i][j][r] = 0.f;

  for (int k0 = 0; k0 < K; k0 += 64) {
    __syncthreads();
#pragma unroll
    for (int r = 0; r < 4; ++r) {
      int rowb = r * 32 + w * 8;  // rows rowb..rowb+7; rowb % 8 == 0
      const ushort_t* ga = A + (size_t)(m0 + rowb + (lane >> 3)) * K + k0 + sw;
      const ushort_t* gb = B + (size_t)(n0 + rowb + (lane >> 3)) * K + k0 + sw;
      __builtin_amdgcn_global_load_lds((gvoid_t*)ga, (lvoid_t*)(As + rowb * 64), 16, 0, 0);
      __builtin_amdgcn_global_load_lds((gvoid_t*)gb, (lvoid_t*)(Bs + rowb * 64), 16, 0, 0);
    }
    __syncthreads();
#pragma unroll
    for (int kk = 0; kk < 2; ++kk) {
      bf16x8 af[4], bfr[4];
#pragma unroll
      for (int i = 0; i < 4; ++i) {
        int row = wm + i * 16 + l15;
        af[i] = *(const bf16x8*)&As[row * 64 + (((kk * 4 + l4) ^ (row & 7)) << 3)];
      }
#pragma unroll
      for (int j = 0; j < 4; ++j) {
        int row = wn + j * 16 + l15;
        bfr[j] = *(const bf16x8*)&Bs[row * 64 + (((kk * 4 + l4) ^ (row & 7)) << 3)];
      }
#pragma unroll
      for (int i = 0; i < 4; ++i)
#pragma unroll
        for (int j = 0; j < 4; ++j)
          acc[i][j] = __builtin_amdgcn_mfma_f32_16x16x32_bf16(af[i], bfr[j], acc[i][j], 0, 0, 0);
    }
  }

  if (n0 >= 2048) {
    // ---- fused V transpose epilogue ----
    __syncthreads();  // all waves done reading As/Bs
#pragma unroll
    for (int i = 0; i < 4; ++i)
#pragma unroll
      for (int j = 0; j < 4; ++j)
#pragma unroll
        for (int r = 0; r < 4; ++r) {
          int rl = wm + i * 16 + l4 * 4 + r;   // token_local 0..127
          int cl = wn + j * 16 + l15;          // col_local 0..127
          smem[rl * 128 + (cl ^ ((rl & 7) << 3))] = f2bf(acc[i][j][r]);
        }
    __syncthreads();
    const int vbase = n0 - 2048;
    const int s0 = m0 >> 1;
#pragma unroll
    for (int q = 0; q < 8; ++q) {
      int lin = q * 256 + tid;
      int cl = lin >> 4, sub = lin & 15;
      int bb = sub >> 3, s8 = (sub & 7) * 8;
      u16x8 o;
#pragma unroll
      for (int e = 0; e < 8; ++e) {
        int tok = (s8 + e) * 2 + bb;
        o[e] = smem[tok * 128 + (cl ^ ((tok & 7) << 3))];
      }
      int vcol = vbase + cl;
      int nn = vcol >> 6, dd = vcol & 63;
      *(u16x8*)(vt + ((size_t)(nn * 2 + bb) * 64 + dd) * 2048 + s0 + s8) = o;
    }
  } else {
    // ---- normal bf16 C write (Q/K columns) ----
#pragma unroll
    for (int i = 0; i < 4; ++i)
#pragma unroll
      for (int j = 0; j < 4; ++j)
#pragma unroll
        for (int r = 0; r < 4; ++r) {
          int row = m0 + wm + i * 16 + l4 * 4 + r;
          int col = n0 + wn + j * 16 + l15;
          C[(size_t)row * N + col] = f2bf(acc[i][j][r]);
        }
  }
}

// ------------- GEMM 64x128 tiles, BK=64 swizzled, bf16 out (512 blocks) -------------
__global__ __launch_bounds__(256) void k_gemm64(const ushort_t* __restrict__ A,
                                                const ushort_t* __restrict__ B,
                                                ushort_t* __restrict__ C, int M, int N, int K,
                                                int nbx) {
  __shared__ __attribute__((aligned(16))) ushort_t As[64 * 64];
  __shared__ __attribute__((aligned(16))) ushort_t Bs[128 * 64];
  const int per = gridDim.x >> 3;
  const int fl = (blockIdx.x & 7) * per + (blockIdx.x >> 3);
  const int m0 = (fl / nbx) * 64, n0 = (fl % nbx) * 128;
  const int tid = threadIdx.x, w = tid >> 6, lane = tid & 63;
  const int wn = w * 32;
  const int l15 = lane & 15, l4 = lane >> 4;
  const int sw = ((lane & 7) ^ (lane >> 3)) << 3;
  f32x4 acc[4][2];
#pragma unroll
  for (int i = 0; i < 4; ++i)
#pragma unroll
    for (int j = 0; j < 2; ++j)
#pragma unroll
      for (int r = 0; r < 4; ++r) acc[i][j][r] = 0.f;

  for (int k0 = 0; k0 < K; k0 += 64) {
    __syncthreads();
#pragma unroll
    for (int r = 0; r < 2; ++r) {  // A rows w*16 + {0,8}
      int rowb = w * 16 + r * 8;
      const ushort_t* ga = A + (size_t)(m0 + rowb + (lane >> 3)) * K + k0 + sw;
      __builtin_amdgcn_global_load_lds((gvoid_t*)ga, (lvoid_t*)(As + rowb * 64), 16, 0, 0);
    }
#pragma unroll
    for (int r = 0; r < 4; ++r) {  // B rows w*32 + {0,8,16,24}
      int rowb = w * 32 + r * 8;
      const ushort_t* gb = B + (size_t)(n0 + rowb + (lane >> 3)) * K + k0 + sw;
      __builtin_amdgcn_global_load_lds((gvoid_t*)gb, (lvoid_t*)(Bs + rowb * 64), 16, 0, 0);
    }
    __syncthreads();
#pragma unroll
    for (int kk = 0; kk < 2; ++kk) {
      bf16x8 af[4], bfr[2];
#pragma unroll
      for (int i = 0; i < 4; ++i) {
        int row = i * 16 + l15;
        af[i] = *(const bf16x8*)&As[row * 64 + (((kk * 4 + l4) ^ (row & 7)) << 3)];
      }
#pragma unroll
      for (int j = 0; j < 2; ++j) {
        int row = wn + j * 16 + l15;
        bfr[j] = *(const bf16x8*)&Bs[row * 64 + (((kk * 4 + l4) ^ (row & 7)) << 3)];
      }
#pragma unroll
      for (int i = 0; i < 4; ++i)
#pragma unroll
        for (int j = 0; j < 2; ++j)
          acc[i][j] = __builtin_amdgcn_mfma_f32_16x16x32_bf16(af[i], bfr[j], acc[i][j], 0, 0, 0);
    }
  }
#pragma unroll
  for (int i = 0; i < 4; ++i)
#pragma unroll
    for (int j = 0; j < 2; ++j)
#pragma unroll
      for (int r = 0; r < 4; ++r)
        C[(size_t)(m0 + i * 16 + l4 * 4 + r) * N + n0 + wn + j * 16 + l15] = f2bf(acc[i][j][r]);
}

// ------------- flash attention, split-KV across blocks, XCD-swizzled 1D grid -------------
// Fixed-max softmax: P = exp(s) (Q prescaled), l via per-lane VALU tree.
// Register-lean (jb-split). LDS[row][s]=src[row][s^g(row)], g(row)=(row&7)^((row>>3)&7).
__global__ __launch_bounds__(256, 4) void k_attn(const ushort_t* __restrict__ qkv,
                                                 const ushort_t* __restrict__ vt,
                                                 ushort_t* o0, ushort_t* o1,
                                                 float* __restrict__ l0,
                                                 float* __restrict__ l1) {
  __shared__ __attribute__((aligned(16))) ushort_t Ks[2][4096];
  __shared__ __attribute__((aligned(16))) ushort_t VTs[2][4096];
  const int bid = blockIdx.x;
  const int fl = (bid & 7) * 128 + (bid >> 3);  // bijective, 1024 % 8 == 0
  const int qb = fl & 15, bn = (fl >> 4) & 31, z = fl >> 9;
  const int b = bn & 1, n = bn >> 1;
  const int tid = threadIdx.x, w = tid >> 6, lane = tid & 63;
  const int l31 = lane & 31, h = lane >> 5;
  const int qrow = qb * 128 + w * 32 + l31;
  const size_t qoff = (size_t)qrow * 6144 + b * 3072 + n * 64;
  const float CEXP = 0.18033688011113723f;  // 0.125 * log2(e)
  bf16x8 qf[4];
#pragma unroll
  for (int ks = 0; ks < 4; ++ks) {
    u16x8 qv = *(const u16x8*)(qkv + qoff + ks * 16 + h * 8);
    union { u16x8 u; bf16x8 v; } cu;
#pragma unroll
    for (int e = 0; e < 8; ++e) cu.u[e] = f2bf(bf2f(qv[e]) * CEXP);
    qf[ks] = cu.v;
  }
  const int fA = (l31 & 7) ^ (l31 >> 3);
  const int fB = fA ^ 4;

  const int t0 = z * 16;  // this block's first KV tile
  const int sw0 = (((lane & 7) ^ (lane >> 3) ^ (w * 2)) & 7) << 3;
  const int sw1 = (((lane & 7) ^ (lane >> 3) ^ (w * 2 + 1)) & 7) << 3;
  const ushort_t* kp0 = qkv + (size_t)(t0 * 64 + w * 16 + (lane >> 3)) * 6144 + b * 3072 + n * 64 + 1024 + sw0;
  const ushort_t* kp1 = qkv + (size_t)(t0 * 64 + w * 16 + 8 + (lane >> 3)) * 6144 + b * 3072 + n * 64 + 1024 + sw1;
  const ushort_t* vp0 = vt + ((size_t)bn * 64 + w * 16 + (lane >> 3)) * 2048 + t0 * 64 + sw0;
  const ushort_t* vp1 = vt + ((size_t)bn * 64 + w * 16 + 8 + (lane >> 3)) * 2048 + t0 * 64 + sw1;
  const size_t KSTRIDE = (size_t)64 * 6144;

  // ---- prologue: stage tile t0 into buffer 0 ----
  __builtin_amdgcn_global_load_lds((gvoid_t*)kp0, (lvoid_t*)(Ks[0] + (w * 16) * 64), 16, 0, 0);
  __builtin_amdgcn_global_load_lds((gvoid_t*)kp1, (lvoid_t*)(Ks[0] + (w * 16 + 8) * 64), 16, 0, 0);
  __builtin_amdgcn_global_load_lds((gvoid_t*)vp0, (lvoid_t*)(VTs[0] + (w * 16) * 64), 16, 0, 0);
  __builtin_amdgcn_global_load_lds((gvoid_t*)vp1, (lvoid_t*)(VTs[0] + (w * 16 + 8) * 64), 16, 0, 0);
  kp0 += KSTRIDE; kp1 += KSTRIDE; vp0 += 64; vp1 += 64;
  __syncthreads();

  f32x16 oacc[2];
#pragma unroll
  for (int r = 0; r < 16; ++r) { oacc[0][r] = 0.f; oacc[1][r] = 0.f; }
  float lsum = 0.f;

  for (int t = 0; t < 16; ++t) {
    const ushort_t* Kb = Ks[t & 1];
    const ushort_t* Vb = VTs[t & 1];
    if (t < 15) {
      ushort_t* kw = Ks[(t + 1) & 1];
      ushort_t* vw = VTs[(t + 1) & 1];
      __builtin_amdgcn_global_load_lds((gvoid_t*)kp0, (lvoid_t*)(kw + (w * 16) * 64), 16, 0, 0);
      __builtin_amdgcn_global_load_lds((gvoid_t*)kp1, (lvoid_t*)(kw + (w * 16 + 8) * 64), 16, 0, 0);
      __builtin_amdgcn_global_load_lds((gvoid_t*)vp0, (lvoid_t*)(vw + (w * 16) * 64), 16, 0, 0);
      __builtin_amdgcn_global_load_lds((gvoid_t*)vp1, (lvoid_t*)(vw + (w * 16 + 8) * 64), 16, 0, 0);
      kp0 += KSTRIDE; kp1 += KSTRIDE; vp0 += 64; vp1 += 64;
    }
    // jb-split: QK(j-half) -> exp -> PV(2 slots) -> l-tree, sv reused per half
#pragma unroll
    for (int jb = 0; jb < 2; ++jb) {
      f32x16 sv;
#pragma unroll
      for (int r = 0; r < 16; ++r) sv[r] = 0.f;
      const int rb = (jb * 32 + l31) * 64;
      const int fj = jb ? fB : fA;
      __builtin_amdgcn_s_setprio(1);
#pragma unroll
      for (int ks = 0; ks < 4; ++ks) {
        bf16x8 kf = *(const bf16x8*)&Kb[rb + ((((ks << 1) | h) ^ fj) << 3)];
        sv = __builtin_amdgcn_mfma_f32_32x32x16_bf16(kf, qf[ks], sv, 0, 0, 0);
      }
      __builtin_amdgcn_s_setprio(0);
#pragma unroll
      for (int r = 0; r < 16; ++r) sv[r] = __builtin_amdgcn_exp2f(sv[r]);
      // PV slots for this j-half
#pragma unroll
      for (int ks2 = 0; ks2 < 2; ++ks2) {
        const int q0 = ks2 * 2;
        uint32 X0, X1, Y0, Y1;
        asm volatile("v_cvt_pk_bf16_f32 %0, %1, %2" : "=v"(X0) : "v"(sv[q0 * 4 + 0]), "v"(sv[q0 * 4 + 1]));
        asm volatile("v_cvt_pk_bf16_f32 %0, %1, %2" : "=v"(X1) : "v"(sv[q0 * 4 + 2]), "v"(sv[q0 * 4 + 3]));
        asm volatile("v_cvt_pk_bf16_f32 %0, %1, %2" : "=v"(Y0) : "v"(sv[(q0 + 1) * 4 + 0]), "v"(sv[(q0 + 1) * 4 + 1]));
        asm volatile("v_cvt_pk_bf16_f32 %0, %1, %2" : "=v"(Y1) : "v"(sv[(q0 + 1) * 4 + 2]), "v"(sv[(q0 + 1) * 4 + 3]));
        asm volatile("v_permlane32_swap_b32 %0, %1" : "+v"(X0), "+v"(Y0));
        asm volatile("v_permlane32_swap_b32 %0, %1" : "+v"(X1), "+v"(Y1));
        union { u32x4 u; bf16x8 v; } pf;
        pf.u[0] = X0; pf.u[1] = X1; pf.u[2] = Y0; pf.u[3] = Y1;
        const int c = ((jb * 2 + ks2) << 1) | h;
        bf16x8 vf0 = *(const bf16x8*)&Vb[l31 * 64 + ((c ^ fA) << 3)];
        bf16x8 vf1 = *(const bf16x8*)&Vb[(32 + l31) * 64 + ((c ^ fB) << 3)];
        __builtin_amdgcn_s_setprio(1);
        oacc[0] = __builtin_amdgcn_mfma_f32_32x32x16_bf16(vf0, pf.v, oacc[0], 0, 0, 0);
        oacc[1] = __builtin_amdgcn_mfma_f32_32x32x16_bf16(vf1, pf.v, oacc[1], 0, 0, 0);
        __builtin_amdgcn_s_setprio(0);
      }
      // l tree for this half (off critical path)
      float ls[8];
#pragma unroll
      for (int r = 0; r < 8; ++r) ls[r] = sv[r] + sv[r + 8];
#pragma unroll
      for (int st = 4; st >= 1; st >>= 1)
#pragma unroll
        for (int r = 0; r < st; ++r) ls[r] += ls[r + st];
      lsum += ls[0];
    }
    if (t < 15) __syncthreads();
  }
  const float l_run = lsum + __shfl_xor(lsum, 32);

  // ---- write RAW partials (bf16 O, fp32 l) ----
  ushort_t* op = (z == 0) ? (o0 + (size_t)qrow * 2048 + b * 1024 + n * 64)
                          : (o1 + (size_t)qrow * 6144 + b * 3072 + 2048 + n * 64);
#pragma unroll
  for (int db = 0; db < 2; ++db)
#pragma unroll
    for (int qq = 0; qq < 4; ++qq) {
      u16x4 st;
#pragma unroll
      for (int m = 0; m < 4; ++m) st[m] = f2bf(oacc[db][qq * 4 + m]);
      *(u16x4*)(op + db * 32 + qq * 8 + h * 4) = st;
    }
  if (h == 0) {
    float* lp = (z == 0) ? l0 : l1;
    lp[qrow * 32 + bn] = l_run;
  }
}

// ------------- combine halves + memory retrieval + gated injection -------------
__global__ __launch_bounds__(256) void k_gate2(const ushort_t* __restrict__ qkv,
                                               const ushort_t* __restrict__ o0,
                                               const float* __restrict__ l0,
                                               const float* __restrict__ l1,
                                               const float* __restrict__ mem,
                                               const float* __restrict__ mnorm,
                                               const float* __restrict__ gbeta,
                                               ushort_t* __restrict__ inj) {
  const int bn = blockIdx.y, b = bn & 1, n = bn >> 1;
  const int tid = threadIdx.x, w = tid >> 6, lane = tid & 63;
  const int l31 = lane & 31, h = lane >> 5;
  const int qrow = blockIdx.x * 128 + w * 32 + l31;
  const size_t qoff = (size_t)qrow * 6144 + b * 3072 + n * 64;

  float den = 0.f;
  bf16x8 cqf[4];
  const float* nrm = mnorm + (size_t)(b * NHEAD + n) * 64;
#pragma unroll
  for (int ks = 0; ks < 4; ++ks) {
    u16x8 qv = *(const u16x8*)(qkv + qoff + ks * 16 + h * 8);
    union { u16x8 u; bf16x8 v; } cu;
#pragma unroll
    for (int e = 0; e < 8; ++e) {
      float x = bf2f(qv[e]);
      float c = (x > 0.f) ? (x + 1.f) : __builtin_amdgcn_exp2f(x * 1.4426950408889634f);
      cu.u[e] = f2bf(c);
      den += c * nrm[ks * 16 + h * 8 + e];
    }
    cqf[ks] = cu.v;
  }
  den += __shfl_xor(den, 32);

  const float* mb = mem + (size_t)(b * NHEAD + n) * 4096;
  f32x16 accv[2];
#pragma unroll
  for (int r = 0; r < 16; ++r) { accv[0][r] = 0.f; accv[1][r] = 0.f; }
#pragma unroll
  for (int db = 0; db < 2; ++db)
#pragma unroll
    for (int ks = 0; ks < 4; ++ks) {
      union { u16x8 u; bf16x8 v; } af;
#pragma unroll
      for (int e = 0; e < 8; ++e)
        af.u[e] = f2bf(mb[(size_t)(ks * 16 + h * 8 + e) * 64 + db * 32 + l31]);
      accv[db] = __builtin_amdgcn_mfma_f32_32x32x16_bf16(af.v, cqf[ks], accv[db], 0, 0, 0);
    }

  const float lsum = l0[qrow * 32 + bn] + l1[qrow * 32 + bn];
  float g = 1.f / (1.f + expf(-gbeta[0]));
  float rden = 1.f / den, invl = 1.f / lsum;
  const ushort_t* p0 = o0 + (size_t)qrow * 2048 + b * 1024 + n * 64;
  const ushort_t* p1 = qkv + (size_t)qrow * 6144 + b * 3072 + 2048 + n * 64;
  ushort_t* op = inj + (size_t)qrow * 2048 + b * 1024 + n * 64;
#pragma unroll
  for (int db = 0; db < 2; ++db)
#pragma unroll
    for (int qq = 0; qq < 4; ++qq) {
      const int off = db * 32 + qq * 8 + h * 4;
      u16x4 a0 = *(const u16x4*)(p0 + off);
      u16x4 a1 = *(const u16x4*)(p1 + off);
      u16x4 st;
#pragma unroll
      for (int m = 0; m < 4; ++m) {
        float av = (bf2f(a0[m]) + bf2f(a1[m])) * invl;
        float content = accv[db][qq * 4 + m] * rden;
        st[m] = f2bf(g * content + (1.f - g) * av);
      }
      *(u16x4*)(op + off) = st;
    }
}

// ------------- y = h + attn_out(bf16); LayerNorm(D=1024) -------------
__global__ __launch_bounds__(256) void k_ln(const float* __restrict__ h,
                                            const ushort_t* __restrict__ aob,
                                            const float* __restrict__ gam,
                                            const float* __restrict__ bet,
                                            float* __restrict__ out) {
  const int m = blockIdx.x, t = threadIdx.x;
  const int lane = t & 63, w = t >> 6;
  __shared__ float redS[4], redQ[4];
  const size_t base = (size_t)m * 1024;
  float4 hv = ((const float4*)(h + base))[t];
  u16x4 av4 = ((const u16x4*)(aob + base))[t];
  float y0 = hv.x + bf2f(av4[0]), y1 = hv.y + bf2f(av4[1]);
  float y2 = hv.z + bf2f(av4[2]), y3 = hv.w + bf2f(av4[3]);
  float s = y0 + y1 + y2 + y3;
  float sq = y0 * y0 + y1 * y1 + y2 * y2 + y3 * y3;
#pragma unroll
  for (int mk = 32; mk >= 1; mk >>= 1) { s += __shfl_xor(s, mk); sq += __shfl_xor(sq, mk); }
  if (lane == 0) { redS[w] = s; redQ[w] = sq; }
  __syncthreads();
  float Ssum = redS[0] + redS[1] + redS[2] + redS[3];
  float Qsum = redQ[0] + redQ[1] + redQ[2] + redQ[3];
  float mu = Ssum * (1.f / 1024.f);
  float var = Qsum * (1.f / 1024.f) - mu * mu;
  float rstd = rsqrtf(var + 1e-5f);
  float4 g = ((const float4*)gam)[t];
  float4 bt = ((const float4*)bet)[t];
  float4 o;
  o.x = (y0 - mu) * rstd * g.x + bt.x;
  o.y = (y1 - mu) * rstd * g.y + bt.y;
  o.z = (y2 - mu) * rstd * g.z + bt.z;
  o.w = (y3 - mu) * rstd * g.w + bt.w;
  ((float4*)(out + base))[t] = o;
}

extern "C" void kernel_launch(void* const* d_in, const int* in_sizes, int n_in,
                              void* d_out, int out_size, void* d_ws, size_t ws_size,
                              hipStream_t stream) {
  const float* h = (const float*)d_in[0];
  const float* Wq = (const float*)d_in[1];
  const float* Wkv = (const float*)d_in[2];
  const float* Wo = (const float*)d_in[3];
  const float* gam = (const float*)d_in[4];
  const float* bet = (const float*)d_in[5];
  const float* mem = (const float*)d_in[6];
  const float* mnorm = (const float*)d_in[7];
  const float* gbeta = (const float*)d_in[8];
  float* out = (float*)d_out;

  char* ws = (char*)d_ws;
  // [0,8M)   hb  (gemm1 A)      -> O0 partials (attn z=0)
  // [8M,14M) wT  (gemm1 B)      -> l0 at [8M,+256K), l1 at [8M+256K,+256K)
  // [14M,16M) woT (gemm2 B)
  // [16M,40M) qkv (V-slots unwritten by gemm1; filled with O1 partials by attn)
  //           -> aob bf16 after gate2
  // [40M,48M) vt  (written by gemm1 fused epilogue) -> inj (gate2 out, gemm2 A)
  ushort_t* hb  = (ushort_t*)(ws);
  ushort_t* wT  = (ushort_t*)(ws + (size_t)(8u << 20));
  ushort_t* woT = (ushort_t*)(ws + (size_t)(14u << 20));
  ushort_t* qkv = (ushort_t*)(ws + (size_t)(16u << 20));
  ushort_t* aob = (ushort_t*)(ws + (size_t)(16u << 20));  // alias qkv (dead by then)
  ushort_t* vtb = (ushort_t*)(ws + (size_t)(40u << 20));
  ushort_t* o0  = hb;                                     // alias hb (dead by then)
  float*    l0  = (float*)(ws + (size_t)(8u << 20));      // alias wT (dead by then)
  float*    l1  = (float*)(ws + (size_t)(8u << 20) + (1u << 18));
  ushort_t* inj = vtb;                                    // alias vt (dead by then)

  k_cvt_all<<<dim3(64, 32, 4), 256, 0, stream>>>(h, Wq, Wkv, Wo, hb, wT, woT);
  k_gemm_bt<<<768, 256, 0, stream>>>(hb, wT, qkv, vtb, 4096, 3072, 1024, 24);
  k_attn<<<1024, 256, 0, stream>>>(qkv, vtb, o0, qkv, l0, l1);
  k_gate2<<<dim3(16, 32), 256, 0, stream>>>(qkv, o0, l0, l1, mem, mnorm, gbeta, inj);
  k_gemm64<<<512, 256, 0, stream>>>(inj, woT, aob, 4096, 1024, 1024, 8);
  k_ln<<<4096, 256, 0, stream>>>(h, aob, gam, bet, out);
}

// Round 16
// 129.578 us; speedup vs baseline: 1.1606x; 1.0070x over previous
//
#include <hip/hip_runtime.h>

// InfiniAttn forward on gfx950.
// cvt (h + 3×W merged, vectorized) | GEMM qkv (BK=64, swizzled LDS; V-blocks write vt
// transposed via LDS epilogue) | flash attn SPLIT-KV (fixed-max, register-lean,
// XCD-swizzled) | combine+mem-gate | GEMM out (32x128, BK=64 swizzled, bf16) | +h,LN.

typedef unsigned short ushort_t;
typedef unsigned int uint32;

typedef __bf16 bf16x8 __attribute__((ext_vector_type(8)));
typedef float f32x4 __attribute__((ext_vector_type(4)));
typedef float f32x16 __attribute__((ext_vector_type(16)));
typedef unsigned short u16x8 __attribute__((ext_vector_type(8)));
typedef unsigned short u16x4 __attribute__((ext_vector_type(4)));
typedef unsigned int u32x4 __attribute__((ext_vector_type(4)));

typedef const __attribute__((address_space(1))) void gvoid_t;
typedef __attribute__((address_space(3))) void lvoid_t;

#define S_LEN 2048
#define BATCH 2
#define NHEAD 16

__device__ __forceinline__ ushort_t f2bf(float x) {
  union { float f; unsigned u; } c; c.f = x;
  unsigned r = (c.u + 0x7FFFu + ((c.u >> 16) & 1u)) >> 16;
  return (ushort_t)r;
}
__device__ __forceinline__ float bf2f(ushort_t v) {
  union { unsigned u; float f; } c; c.u = ((unsigned)v) << 16;
  return c.f;
}

// ------------- merged convert: z<3 -> W transpose-convert; z==3 -> h fp32->bf16 -------------
__global__ __launch_bounds__(256) void k_cvt_all(const float* __restrict__ h,
                                                 const float* __restrict__ Wq,
                                                 const float* __restrict__ Wkv,
                                                 const float* __restrict__ Wo,
                                                 ushort_t* __restrict__ hb,
                                                 ushort_t* __restrict__ wT,
                                                 ushort_t* __restrict__ woT) {
  const int z = blockIdx.z;
  if (z == 3) {  // h convert: 2048 blocks x 256 thr x 2 float4
    int idx = (blockIdx.y * 64 + blockIdx.x) * 256 + threadIdx.x;
#pragma unroll
    for (int i = 0; i < 2; ++i) {
      int e = idx + i * 524288;
      float4 v = ((const float4*)h)[e];
      u16x4 o; o[0] = f2bf(v.x); o[1] = f2bf(v.y); o[2] = f2bf(v.z); o[3] = f2bf(v.w);
      ((u16x4*)hb)[e] = o;
    }
    return;
  }
  const float* W;
  ushort_t* WT;
  int N;
  if (z == 0)      { W = Wq;  WT = wT;                        N = 1024; }
  else if (z == 1) { W = Wkv; WT = wT + (size_t)1024 * 1024;  N = 2048; }
  else             { W = Wo;  WT = woT;                       N = 1024; }
  const int K = 1024;
  if (blockIdx.x * 32 >= N) return;
  __shared__ float tile[32][33];
  const int n0 = blockIdx.x * 32, k0 = blockIdx.y * 32;
  // vectorized load: 8 threads/row x 32 rows, float4 each
  {
    const int ty = threadIdx.x >> 3, tx4 = (threadIdx.x & 7) * 4;
    float4 v = *(const float4*)(W + (size_t)(k0 + ty) * N + n0 + tx4);
    tile[ty][tx4 + 0] = v.x; tile[ty][tx4 + 1] = v.y;
    tile[ty][tx4 + 2] = v.z; tile[ty][tx4 + 3] = v.w;
  }
  __syncthreads();
  const int tx = threadIdx.x & 31, ty = threadIdx.x >> 5;
#pragma unroll
  for (int r = 0; r < 32; r += 8)
    WT[(size_t)(n0 + ty + r) * K + k0 + tx] = f2bf(tile[tx][ty + r]);
}

// ------------- GEMM 128x128, BK=64: qkv = hb * wT^T; V-blocks write vt transposed -------------
// Main loop LDS [128 rows][8 slots x 8 shorts]; LDS[row][s] = src[row][s ^ (row&7)].
__global__ __launch_bounds__(256) void k_gemm_bt(const ushort_t* __restrict__ A,
                                                 const ushort_t* __restrict__ B,
                                                 ushort_t* __restrict__ C,
                                                 ushort_t* __restrict__ vt,
                                                 int M, int N, int K, int nbx) {
  __shared__ __attribute__((aligned(16))) ushort_t smem[16384];
  ushort_t* As = smem;
  ushort_t* Bs = smem + 8192;
  const int per = gridDim.x >> 3;  // grid % 8 == 0
  const int fl = (blockIdx.x & 7) * per + (blockIdx.x >> 3);
  const int m0 = (fl / nbx) * 128, n0 = (fl % nbx) * 128;
  const int tid = threadIdx.x, w = tid >> 6, lane = tid & 63;
  const int wm = (w >> 1) * 64, wn = (w & 1) * 64;
  const int l15 = lane & 15, l4 = lane >> 4;
  const int sw = ((lane & 7) ^ (lane >> 3)) << 3;  // source col pre-swizzle (shorts)
  f32x4 acc[4][4];
#pragma unroll
  for (int i = 0; i < 4; ++i)
#pragma unroll
    for (int j = 0; j < 4; ++j)
#pragma unroll
      for (int r = 0; r < 4; ++r) acc[i][j][r] = 0.f;

  for (int k0 = 0; k0 < K; k0 += 64) {
    __syncthreads();
#pragma unroll
    for (int r = 0; r < 4; ++r) {
      int rowb = r * 32 + w * 8;  // rows rowb..rowb+7; rowb % 8 == 0
      const ushort_t* ga = A + (size_t)(m0 + rowb + (lane >> 3)) * K + k0 + sw;
      const ushort_t* gb = B + (size_t)(n0 + rowb + (lane >> 3)) * K + k0 + sw;
      __builtin_amdgcn_global_load_lds((gvoid_t*)ga, (lvoid_t*)(As + rowb * 64), 16, 0, 0);
      __builtin_amdgcn_global_load_lds((gvoid_t*)gb, (lvoid_t*)(Bs + rowb * 64), 16, 0, 0);
    }
    __syncthreads();
#pragma unroll
    for (int kk = 0; kk < 2; ++kk) {
      bf16x8 af[4], bfr[4];
#pragma unroll
      for (int i = 0; i < 4; ++i) {
        int row = wm + i * 16 + l15;
        af[i] = *(const bf16x8*)&As[row * 64 + (((kk * 4 + l4) ^ (row & 7)) << 3)];
      }
#pragma unroll
      for (int j = 0; j < 4; ++j) {
        int row = wn + j * 16 + l15;
        bfr[j] = *(const bf16x8*)&Bs[row * 64 + (((kk * 4 + l4) ^ (row & 7)) << 3)];
      }
#pragma unroll
      for (int i = 0; i < 4; ++i)
#pragma unroll
        for (int j = 0; j < 4; ++j)
          acc[i][j] = __builtin_amdgcn_mfma_f32_16x16x32_bf16(af[i], bfr[j], acc[i][j], 0, 0, 0);
    }
  }

  if (n0 >= 2048) {
    // ---- fused V transpose epilogue ----
    __syncthreads();  // all waves done reading As/Bs
#pragma unroll
    for (int i = 0; i < 4; ++i)
#pragma unroll
      for (int j = 0; j < 4; ++j)
#pragma unroll
        for (int r = 0; r < 4; ++r) {
          int rl = wm + i * 16 + l4 * 4 + r;   // token_local 0..127
          int cl = wn + j * 16 + l15;          // col_local 0..127
          smem[rl * 128 + (cl ^ ((rl & 7) << 3))] = f2bf(acc[i][j][r]);
        }
    __syncthreads();
    const int vbase = n0 - 2048;
    const int s0 = m0 >> 1;
#pragma unroll
    for (int q = 0; q < 8; ++q) {
      int lin = q * 256 + tid;
      int cl = lin >> 4, sub = lin & 15;
      int bb = sub >> 3, s8 = (sub & 7) * 8;
      u16x8 o;
#pragma unroll
      for (int e = 0; e < 8; ++e) {
        int tok = (s8 + e) * 2 + bb;
        o[e] = smem[tok * 128 + (cl ^ ((tok & 7) << 3))];
      }
      int vcol = vbase + cl;
      int nn = vcol >> 6, dd = vcol & 63;
      *(u16x8*)(vt + ((size_t)(nn * 2 + bb) * 64 + dd) * 2048 + s0 + s8) = o;
    }
  } else {
    // ---- normal bf16 C write (Q/K columns) ----
#pragma unroll
    for (int i = 0; i < 4; ++i)
#pragma unroll
      for (int j = 0; j < 4; ++j)
#pragma unroll
        for (int r = 0; r < 4; ++r) {
          int row = m0 + wm + i * 16 + l4 * 4 + r;
          int col = n0 + wn + j * 16 + l15;
          C[(size_t)row * N + col] = f2bf(acc[i][j][r]);
        }
  }
}

// ------------- GEMM 32x128 tiles, BK=64 swizzled, bf16 out (1024 blocks = 4/CU) -------------
__global__ __launch_bounds__(256) void k_gemm64(const ushort_t* __restrict__ A,
                                                const ushort_t* __restrict__ B,
                                                ushort_t* __restrict__ C, int M, int N, int K,
                                                int nbx) {
  __shared__ __attribute__((aligned(16))) ushort_t As[32 * 64];
  __shared__ __attribute__((aligned(16))) ushort_t Bs[128 * 64];
  const int per = gridDim.x >> 3;
  const int fl = (blockIdx.x & 7) * per + (blockIdx.x >> 3);
  const int m0 = (fl / nbx) * 32, n0 = (fl % nbx) * 128;
  const int tid = threadIdx.x, w = tid >> 6, lane = tid & 63;
  const int wn = w * 32;
  const int l15 = lane & 15, l4 = lane >> 4;
  const int sw = ((lane & 7) ^ (lane >> 3)) << 3;
  f32x4 acc[2][2];
#pragma unroll
  for (int i = 0; i < 2; ++i)
#pragma unroll
    for (int j = 0; j < 2; ++j)
#pragma unroll
      for (int r = 0; r < 4; ++r) acc[i][j][r] = 0.f;

  for (int k0 = 0; k0 < K; k0 += 64) {
    __syncthreads();
    {  // A rows w*8..w*8+7 (32 rows total across 4 waves)
      int rowb = w * 8;
      const ushort_t* ga = A + (size_t)(m0 + rowb + (lane >> 3)) * K + k0 + sw;
      __builtin_amdgcn_global_load_lds((gvoid_t*)ga, (lvoid_t*)(As + rowb * 64), 16, 0, 0);
    }
#pragma unroll
    for (int r = 0; r < 4; ++r) {  // B rows w*32 + {0,8,16,24}
      int rowb = w * 32 + r * 8;
      const ushort_t* gb = B + (size_t)(n0 + rowb + (lane >> 3)) * K + k0 + sw;
      __builtin_amdgcn_global_load_lds((gvoid_t*)gb, (lvoid_t*)(Bs + rowb * 64), 16, 0, 0);
    }
    __syncthreads();
#pragma unroll
    for (int kk = 0; kk < 2; ++kk) {
      bf16x8 af[2], bfr[2];
#pragma unroll
      for (int i = 0; i < 2; ++i) {
        int row = i * 16 + l15;
        af[i] = *(const bf16x8*)&As[row * 64 + (((kk * 4 + l4) ^ (row & 7)) << 3)];
      }
#pragma unroll
      for (int j = 0; j < 2; ++j) {
        int row = wn + j * 16 + l15;
        bfr[j] = *(const bf16x8*)&Bs[row * 64 + (((kk * 4 + l4) ^ (row & 7)) << 3)];
      }
#pragma unroll
      for (int i = 0; i < 2; ++i)
#pragma unroll
        for (int j = 0; j < 2; ++j)
          acc[i][j] = __builtin_amdgcn_mfma_f32_16x16x32_bf16(af[i], bfr[j], acc[i][j], 0, 0, 0);
    }
  }
#pragma unroll
  for (int i = 0; i < 2; ++i)
#pragma unroll
    for (int j = 0; j < 2; ++j)
#pragma unroll
      for (int r = 0; r < 4; ++r)
        C[(size_t)(m0 + i * 16 + l4 * 4 + r) * N + n0 + wn + j * 16 + l15] = f2bf(acc[i][j][r]);
}

// ------------- flash attention, split-KV across blocks, XCD-swizzled 1D grid -------------
// Fixed-max softmax: P = exp(s) (Q prescaled), l via per-lane VALU tree.
// Register-lean (jb-split). LDS[row][s]=src[row][s^g(row)], g(row)=(row&7)^((row>>3)&7).
__global__ __launch_bounds__(256, 4) void k_attn(const ushort_t* __restrict__ qkv,
                                                 const ushort_t* __restrict__ vt,
                                                 ushort_t* o0, ushort_t* o1,
                                                 float* __restrict__ l0,
                                                 float* __restrict__ l1) {
  __shared__ __attribute__((aligned(16))) ushort_t Ks[2][4096];
  __shared__ __attribute__((aligned(16))) ushort_t VTs[2][4096];
  const int bid = blockIdx.x;
  const int fl = (bid & 7) * 128 + (bid >> 3);  // bijective, 1024 % 8 == 0
  const int qb = fl & 15, bn = (fl >> 4) & 31, z = fl >> 9;
  const int b = bn & 1, n = bn >> 1;
  const int tid = threadIdx.x, w = tid >> 6, lane = tid & 63;
  const int l31 = lane & 31, h = lane >> 5;
  const int qrow = qb * 128 + w * 32 + l31;
  const size_t qoff = (size_t)qrow * 6144 + b * 3072 + n * 64;
  const float CEXP = 0.18033688011113723f;  // 0.125 * log2(e)
  bf16x8 qf[4];
#pragma unroll
  for (int ks = 0; ks < 4; ++ks) {
    u16x8 qv = *(const u16x8*)(qkv + qoff + ks * 16 + h * 8);
    union { u16x8 u; bf16x8 v; } cu;
#pragma unroll
    for (int e = 0; e < 8; ++e) cu.u[e] = f2bf(bf2f(qv[e]) * CEXP);
    qf[ks] = cu.v;
  }
  const int fA = (l31 & 7) ^ (l31 >> 3);
  const int fB = fA ^ 4;

  const int t0 = z * 16;  // this block's first KV tile
  const int sw0 = (((lane & 7) ^ (lane >> 3) ^ (w * 2)) & 7) << 3;
  const int sw1 = (((lane & 7) ^ (lane >> 3) ^ (w * 2 + 1)) & 7) << 3;
  const ushort_t* kp0 = qkv + (size_t)(t0 * 64 + w * 16 + (lane >> 3)) * 6144 + b * 3072 + n * 64 + 1024 + sw0;
  const ushort_t* kp1 = qkv + (size_t)(t0 * 64 + w * 16 + 8 + (lane >> 3)) * 6144 + b * 3072 + n * 64 + 1024 + sw1;
  const ushort_t* vp0 = vt + ((size_t)bn * 64 + w * 16 + (lane >> 3)) * 2048 + t0 * 64 + sw0;
  const ushort_t* vp1 = vt + ((size_t)bn * 64 + w * 16 + 8 + (lane >> 3)) * 2048 + t0 * 64 + sw1;
  const size_t KSTRIDE = (size_t)64 * 6144;

  // ---- prologue: stage tile t0 into buffer 0 ----
  __builtin_amdgcn_global_load_lds((gvoid_t*)kp0, (lvoid_t*)(Ks[0] + (w * 16) * 64), 16, 0, 0);
  __builtin_amdgcn_global_load_lds((gvoid_t*)kp1, (lvoid_t*)(Ks[0] + (w * 16 + 8) * 64), 16, 0, 0);
  __builtin_amdgcn_global_load_lds((gvoid_t*)vp0, (lvoid_t*)(VTs[0] + (w * 16) * 64), 16, 0, 0);
  __builtin_amdgcn_global_load_lds((gvoid_t*)vp1, (lvoid_t*)(VTs[0] + (w * 16 + 8) * 64), 16, 0, 0);
  kp0 += KSTRIDE; kp1 += KSTRIDE; vp0 += 64; vp1 += 64;
  __syncthreads();

  f32x16 oacc[2];
#pragma unroll
  for (int r = 0; r < 16; ++r) { oacc[0][r] = 0.f; oacc[1][r] = 0.f; }
  float lsum = 0.f;

  for (int t = 0; t < 16; ++t) {
    const ushort_t* Kb = Ks[t & 1];
    const ushort_t* Vb = VTs[t & 1];
    if (t < 15) {
      ushort_t* kw = Ks[(t + 1) & 1];
      ushort_t* vw = VTs[(t + 1) & 1];
      __builtin_amdgcn_global_load_lds((gvoid_t*)kp0, (lvoid_t*)(kw + (w * 16) * 64), 16, 0, 0);
      __builtin_amdgcn_global_load_lds((gvoid_t*)kp1, (lvoid_t*)(kw + (w * 16 + 8) * 64), 16, 0, 0);
      __builtin_amdgcn_global_load_lds((gvoid_t*)vp0, (lvoid_t*)(vw + (w * 16) * 64), 16, 0, 0);
      __builtin_amdgcn_global_load_lds((gvoid_t*)vp1, (lvoid_t*)(vw + (w * 16 + 8) * 64), 16, 0, 0);
      kp0 += KSTRIDE; kp1 += KSTRIDE; vp0 += 64; vp1 += 64;
    }
    // jb-split: QK(j-half) -> exp -> PV(2 slots) -> l-tree, sv reused per half
#pragma unroll
    for (int jb = 0; jb < 2; ++jb) {
      f32x16 sv;
#pragma unroll
      for (int r = 0; r < 16; ++r) sv[r] = 0.f;
      const int rb = (jb * 32 + l31) * 64;
      const int fj = jb ? fB : fA;
      __builtin_amdgcn_s_setprio(1);
#pragma unroll
      for (int ks = 0; ks < 4; ++ks) {
        bf16x8 kf = *(const bf16x8*)&Kb[rb + ((((ks << 1) | h) ^ fj) << 3)];
        sv = __builtin_amdgcn_mfma_f32_32x32x16_bf16(kf, qf[ks], sv, 0, 0, 0);
      }
      __builtin_amdgcn_s_setprio(0);
#pragma unroll
      for (int r = 0; r < 16; ++r) sv[r] = __builtin_amdgcn_exp2f(sv[r]);
      // PV slots for this j-half
#pragma unroll
      for (int ks2 = 0; ks2 < 2; ++ks2) {
        const int q0 = ks2 * 2;
        uint32 X0, X1, Y0, Y1;
        asm volatile("v_cvt_pk_bf16_f32 %0, %1, %2" : "=v"(X0) : "v"(sv[q0 * 4 + 0]), "v"(sv[q0 * 4 + 1]));
        asm volatile("v_cvt_pk_bf16_f32 %0, %1, %2" : "=v"(X1) : "v"(sv[q0 * 4 + 2]), "v"(sv[q0 * 4 + 3]));
        asm volatile("v_cvt_pk_bf16_f32 %0, %1, %2" : "=v"(Y0) : "v"(sv[(q0 + 1) * 4 + 0]), "v"(sv[(q0 + 1) * 4 + 1]));
        asm volatile("v_cvt_pk_bf16_f32 %0, %1, %2" : "=v"(Y1) : "v"(sv[(q0 + 1) * 4 + 2]), "v"(sv[(q0 + 1) * 4 + 3]));
        asm volatile("v_permlane32_swap_b32 %0, %1" : "+v"(X0), "+v"(Y0));
        asm volatile("v_permlane32_swap_b32 %0, %1" : "+v"(X1), "+v"(Y1));
        union { u32x4 u; bf16x8 v; } pf;
        pf.u[0] = X0; pf.u[1] = X1; pf.u[2] = Y0; pf.u[3] = Y1;
        const int c = ((jb * 2 + ks2) << 1) | h;
        bf16x8 vf0 = *(const bf16x8*)&Vb[l31 * 64 + ((c ^ fA) << 3)];
        bf16x8 vf1 = *(const bf16x8*)&Vb[(32 + l31) * 64 + ((c ^ fB) << 3)];
        __builtin_amdgcn_s_setprio(1);
        oacc[0] = __builtin_amdgcn_mfma_f32_32x32x16_bf16(vf0, pf.v, oacc[0], 0, 0, 0);
        oacc[1] = __builtin_amdgcn_mfma_f32_32x32x16_bf16(vf1, pf.v, oacc[1], 0, 0, 0);
        __builtin_amdgcn_s_setprio(0);
      }
      // l tree for this half (off critical path)
      float ls[8];
#pragma unroll
      for (int r = 0; r < 8; ++r) ls[r] = sv[r] + sv[r + 8];
#pragma unroll
      for (int st = 4; st >= 1; st >>= 1)
#pragma unroll
        for (int r = 0; r < st; ++r) ls[r] += ls[r + st];
      lsum += ls[0];
    }
    if (t < 15) __syncthreads();
  }
  const float l_run = lsum + __shfl_xor(lsum, 32);

  // ---- write RAW partials (bf16 O, fp32 l) ----
  ushort_t* op = (z == 0) ? (o0 + (size_t)qrow * 2048 + b * 1024 + n * 64)
                          : (o1 + (size_t)qrow * 6144 + b * 3072 + 2048 + n * 64);
#pragma unroll
  for (int db = 0; db < 2; ++db)
#pragma unroll
    for (int qq = 0; qq < 4; ++qq) {
      u16x4 st;
#pragma unroll
      for (int m = 0; m < 4; ++m) st[m] = f2bf(oacc[db][qq * 4 + m]);
      *(u16x4*)(op + db * 32 + qq * 8 + h * 4) = st;
    }
  if (h == 0) {
    float* lp = (z == 0) ? l0 : l1;
    lp[qrow * 32 + bn] = l_run;
  }
}

// ------------- combine halves + memory retrieval + gated injection -------------
__global__ __launch_bounds__(256) void k_gate2(const ushort_t* __restrict__ qkv,
                                               const ushort_t* __restrict__ o0,
                                               const float* __restrict__ l0,
                                               const float* __restrict__ l1,
                                               const float* __restrict__ mem,
                                               const float* __restrict__ mnorm,
                                               const float* __restrict__ gbeta,
                                               ushort_t* __restrict__ inj) {
  const int bn = blockIdx.y, b = bn & 1, n = bn >> 1;
  const int tid = threadIdx.x, w = tid >> 6, lane = tid & 63;
  const int l31 = lane & 31, h = lane >> 5;
  const int qrow = blockIdx.x * 128 + w * 32 + l31;
  const size_t qoff = (size_t)qrow * 6144 + b * 3072 + n * 64;

  float den = 0.f;
  bf16x8 cqf[4];
  const float* nrm = mnorm + (size_t)(b * NHEAD + n) * 64;
#pragma unroll
  for (int ks = 0; ks < 4; ++ks) {
    u16x8 qv = *(const u16x8*)(qkv + qoff + ks * 16 + h * 8);
    union { u16x8 u; bf16x8 v; } cu;
#pragma unroll
    for (int e = 0; e < 8; ++e) {
      float x = bf2f(qv[e]);
      float c = (x > 0.f) ? (x + 1.f) : __builtin_amdgcn_exp2f(x * 1.4426950408889634f);
      cu.u[e] = f2bf(c);
      den += c * nrm[ks * 16 + h * 8 + e];
    }
    cqf[ks] = cu.v;
  }
  den += __shfl_xor(den, 32);

  const float* mb = mem + (size_t)(b * NHEAD + n) * 4096;
  f32x16 accv[2];
#pragma unroll
  for (int r = 0; r < 16; ++r) { accv[0][r] = 0.f; accv[1][r] = 0.f; }
#pragma unroll
  for (int db = 0; db < 2; ++db)
#pragma unroll
    for (int ks = 0; ks < 4; ++ks) {
      union { u16x8 u; bf16x8 v; } af;
#pragma unroll
      for (int e = 0; e < 8; ++e)
        af.u[e] = f2bf(mb[(size_t)(ks * 16 + h * 8 + e) * 64 + db * 32 + l31]);
      accv[db] = __builtin_amdgcn_mfma_f32_32x32x16_bf16(af.v, cqf[ks], accv[db], 0, 0, 0);
    }

  const float lsum = l0[qrow * 32 + bn] + l1[qrow * 32 + bn];
  float g = 1.f / (1.f + expf(-gbeta[0]));
  float rden = 1.f / den, invl = 1.f / lsum;
  const ushort_t* p0 = o0 + (size_t)qrow * 2048 + b * 1024 + n * 64;
  const ushort_t* p1 = qkv + (size_t)qrow * 6144 + b * 3072 + 2048 + n * 64;
  ushort_t* op = inj + (size_t)qrow * 2048 + b * 1024 + n * 64;
#pragma unroll
  for (int db = 0; db < 2; ++db)
#pragma unroll
    for (int qq = 0; qq < 4; ++qq) {
      const int off = db * 32 + qq * 8 + h * 4;
      u16x4 a0 = *(const u16x4*)(p0 + off);
      u16x4 a1 = *(const u16x4*)(p1 + off);
      u16x4 st;
#pragma unroll
      for (int m = 0; m < 4; ++m) {
        float av = (bf2f(a0[m]) + bf2f(a1[m])) * invl;
        float content = accv[db][qq * 4 + m] * rden;
        st[m] = f2bf(g * content + (1.f - g) * av);
      }
      *(u16x4*)(op + off) = st;
    }
}

// ------------- y = h + attn_out(bf16); LayerNorm(D=1024) -------------
__global__ __launch_bounds__(256) void k_ln(const float* __restrict__ h,
                                            const ushort_t* __restrict__ aob,
                                            const float* __restrict__ gam,
                                            const float* __restrict__ bet,
                                            float* __restrict__ out) {
  const int m = blockIdx.x, t = threadIdx.x;
  const int lane = t & 63, w = t >> 6;
  __shared__ float redS[4], redQ[4];
  const size_t base = (size_t)m * 1024;
  float4 hv = ((const float4*)(h + base))[t];
  u16x4 av4 = ((const u16x4*)(aob + base))[t];
  float y0 = hv.x + bf2f(av4[0]), y1 = hv.y + bf2f(av4[1]);
  float y2 = hv.z + bf2f(av4[2]), y3 = hv.w + bf2f(av4[3]);
  float s = y0 + y1 + y2 + y3;
  float sq = y0 * y0 + y1 * y1 + y2 * y2 + y3 * y3;
#pragma unroll
  for (int mk = 32; mk >= 1; mk >>= 1) { s += __shfl_xor(s, mk); sq += __shfl_xor(sq, mk); }
  if (lane == 0) { redS[w] = s; redQ[w] = sq; }
  __syncthreads();
  float Ssum = redS[0] + redS[1] + redS[2] + redS[3];
  float Qsum = redQ[0] + redQ[1] + redQ[2] + redQ[3];
  float mu = Ssum * (1.f / 1024.f);
  float var = Qsum * (1.f / 1024.f) - mu * mu;
  float rstd = rsqrtf(var + 1e-5f);
  float4 g = ((const float4*)gam)[t];
  float4 bt = ((const float4*)bet)[t];
  float4 o;
  o.x = (y0 - mu) * rstd * g.x + bt.x;
  o.y = (y1 - mu) * rstd * g.y + bt.y;
  o.z = (y2 - mu) * rstd * g.z + bt.z;
  o.w = (y3 - mu) * rstd * g.w + bt.w;
  ((float4*)(out + base))[t] = o;
}

extern "C" void kernel_launch(void* const* d_in, const int* in_sizes, int n_in,
                              void* d_out, int out_size, void* d_ws, size_t ws_size,
                              hipStream_t stream) {
  const float* h = (const float*)d_in[0];
  const float* Wq = (const float*)d_in[1];
  const float* Wkv = (const float*)d_in[2];
  const float* Wo = (const float*)d_in[3];
  const float* gam = (const float*)d_in[4];
  const float* bet = (const float*)d_in[5];
  const float* mem = (const float*)d_in[6];
  const float* mnorm = (const float*)d_in[7];
  const float* gbeta = (const float*)d_in[8];
  float* out = (float*)d_out;

  char* ws = (char*)d_ws;
  // [0,8M)   hb  (gemm1 A)      -> O0 partials (attn z=0)
  // [8M,14M) wT  (gemm1 B)      -> l0 at [8M,+256K), l1 at [8M+256K,+256K)
  // [14M,16M) woT (gemm2 B)
  // [16M,40M) qkv (V-slots unwritten by gemm1; filled with O1 partials by attn)
  //           -> aob bf16 after gate2
  // [40M,48M) vt  (written by gemm1 fused epilogue) -> inj (gate2 out, gemm2 A)
  ushort_t* hb  = (ushort_t*)(ws);
  ushort_t* wT  = (ushort_t*)(ws + (size_t)(8u << 20));
  ushort_t* woT = (ushort_t*)(ws + (size_t)(14u << 20));
  ushort_t* qkv = (ushort_t*)(ws + (size_t)(16u << 20));
  ushort_t* aob = (ushort_t*)(ws + (size_t)(16u << 20));  // alias qkv (dead by then)
  ushort_t* vtb = (ushort_t*)(ws + (size_t)(40u << 20));
  ushort_t* o0  = hb;                                     // alias hb (dead by then)
  float*    l0  = (float*)(ws + (size_t)(8u << 20));      // alias wT (dead by then)
  float*    l1  = (float*)(ws + (size_t)(8u << 20) + (1u << 18));
  ushort_t* inj = vtb;                                    // alias vt (dead by then)

  k_cvt_all<<<dim3(64, 32, 4), 256, 0, stream>>>(h, Wq, Wkv, Wo, hb, wT, woT);
  k_gemm_bt<<<768, 256, 0, stream>>>(hb, wT, qkv, vtb, 4096, 3072, 1024, 24);
  k_attn<<<1024, 256, 0, stream>>>(qkv, vtb, o0, qkv, l0, l1);
  k_gate2<<<dim3(16, 32), 256, 0, stream>>>(qkv, o0, l0, l1, mem, mnorm, gbeta, inj);
  k_gemm64<<<1024, 256, 0, stream>>>(inj, woT, aob, 4096, 1024, 1024, 8);
  k_ln<<<4096, 256, 0, stream>>>(h, aob, gam, bet, out);
}